// Round 1
// baseline (3542.587 us; speedup 1.0000x reference)
//
#include <hip/hip_runtime.h>

#define F 128

// ---------------- degree ----------------
__global__ __launch_bounds__(256) void k_count_deg(const int* __restrict__ dst,
                                                   float* __restrict__ deg, int E) {
  int e = blockIdx.x * 256 + threadIdx.x;
  if (e < E) atomicAdd(&deg[dst[e]], 1.0f);
}

__global__ __launch_bounds__(256) void k_dis(float* __restrict__ deg, int N) {
  int n = blockIdx.x * 256 + threadIdx.x;
  if (n < N) deg[n] = rsqrtf(deg[n] + 1.0f);
}

// ---------------- GEMM: H[N,128] = X[N,128] @ W[128,128] ----------------
// 32-row x 128-col tile per block (256 thr). Thread = 4 rows x 4 cols.
// x tile staged in LDS (16 KB); W read through L1/L2 (64 KB, hot).
__global__ __launch_bounds__(256) void k_gemm128(const float* __restrict__ X,
                                                 const float* __restrict__ W,
                                                 float* __restrict__ H, int N) {
  __shared__ float xs[32][F];
  const int row0 = blockIdx.x * 32;
  const int tid = threadIdx.x;

  #pragma unroll
  for (int j = 0; j < 16; ++j) {
    int idx = tid + j * 256;          // 0..4095
    int r = idx >> 7, c = idx & 127;
    int gr = row0 + r;
    xs[r][c] = (gr < N) ? X[(size_t)gr * F + c] : 0.0f;
  }
  __syncthreads();

  const int cg = (tid & 31) * 4;      // col base
  const int rg = (tid >> 5) * 4;      // row base (in tile)
  float acc[4][4] = {};

  for (int k = 0; k < F; k += 4) {
    float4 xv[4];
    #pragma unroll
    for (int i = 0; i < 4; ++i) xv[i] = *(const float4*)&xs[rg + i][k];
    #pragma unroll
    for (int kk = 0; kk < 4; ++kk) {
      float4 wv = *(const float4*)&W[(k + kk) * F + cg];
      #pragma unroll
      for (int i = 0; i < 4; ++i) {
        float xi = (kk == 0) ? xv[i].x : (kk == 1) ? xv[i].y : (kk == 2) ? xv[i].z : xv[i].w;
        acc[i][0] += xi * wv.x;
        acc[i][1] += xi * wv.y;
        acc[i][2] += xi * wv.z;
        acc[i][3] += xi * wv.w;
      }
    }
  }

  #pragma unroll
  for (int i = 0; i < 4; ++i) {
    int gr = row0 + rg + i;
    if (gr < N)
      *(float4*)&H[(size_t)gr * F + cg] = make_float4(acc[i][0], acc[i][1], acc[i][2], acc[i][3]);
  }
}

// ---------------- agg init: agg[n,f] = H[n,f] * dis[n]^2 (self-loop term) ----------------
__global__ __launch_bounds__(256) void k_init_agg(const float* __restrict__ H,
                                                  const float* __restrict__ dis,
                                                  float* __restrict__ agg, int N) {
  int i = blockIdx.x * 256 + threadIdx.x;   // float4 index
  int total = N * (F / 4);
  if (i >= total) return;
  int n = i >> 5;                           // F/4 == 32
  float d = dis[n];
  float d2 = d * d;
  float4 h = ((const float4*)H)[i];
  ((float4*)agg)[i] = make_float4(h.x * d2, h.y * d2, h.z * d2, h.w * d2);
}

// ---------------- edge scatter: agg[dst] += H[src] * dis[src]*dis[dst] ----------------
// 2 edges per wave: 32 lanes x float4 covers 128 feats of one edge.
__global__ __launch_bounds__(256) void k_scatter(const float* __restrict__ H,
                                                 const int* __restrict__ src,
                                                 const int* __restrict__ dst,
                                                 const float* __restrict__ dis,
                                                 float* __restrict__ agg, int E) {
  int e = blockIdx.x * 8 + (threadIdx.x >> 5);
  if (e >= E) return;
  int l4 = threadIdx.x & 31;
  int s = src[e], d = dst[e];
  float norm = dis[s] * dis[d];
  float4 h = ((const float4*)(H + (size_t)s * F))[l4];
  float* a = agg + (size_t)d * F + l4 * 4;
  atomicAdd(a + 0, h.x * norm);
  atomicAdd(a + 1, h.y * norm);
  atomicAdd(a + 2, h.z * norm);
  atomicAdd(a + 3, h.w * norm);
}

// ---------------- fused bias + LayerNorm + ReLU (in place), one wave per node ----------------
__global__ __launch_bounds__(256) void k_ln_relu(float* __restrict__ agg,
                                                 const float* __restrict__ bias,
                                                 const float* __restrict__ gamma,
                                                 const float* __restrict__ beta, int N) {
  int n = blockIdx.x * 4 + (threadIdx.x >> 6);
  int lane = threadIdx.x & 63;
  if (n >= N) return;
  float v0 = agg[(size_t)n * F + lane]      + bias[lane];
  float v1 = agg[(size_t)n * F + lane + 64] + bias[lane + 64];
  float s = v0 + v1;
  #pragma unroll
  for (int o = 1; o < 64; o <<= 1) s += __shfl_xor(s, o);
  float mu = s * (1.0f / F);
  float d0 = v0 - mu, d1 = v1 - mu;
  float sq = d0 * d0 + d1 * d1;
  #pragma unroll
  for (int o = 1; o < 64; o <<= 1) sq += __shfl_xor(sq, o);
  float inv = rsqrtf(sq * (1.0f / F) + 1e-5f);
  float o0 = d0 * inv * gamma[lane]      + beta[lane];
  float o1 = d1 * inv * gamma[lane + 64] + beta[lane + 64];
  agg[(size_t)n * F + lane]      = fmaxf(o0, 0.0f);
  agg[(size_t)n * F + lane + 64] = fmaxf(o1, 0.0f);
}

// ---------------- layer 3: h3[n] = ln2[n,:]·W3 ; out[n] = h3[n]*dis^2 + b3 ----------------
__global__ __launch_bounds__(256) void k_layer3(const float* __restrict__ ln2,
                                                const float* __restrict__ W3,
                                                const float* __restrict__ b3,
                                                const float* __restrict__ dis,
                                                float* __restrict__ h3,
                                                float* __restrict__ out, int N) {
  int n = blockIdx.x * 4 + (threadIdx.x >> 6);
  int lane = threadIdx.x & 63;
  if (n >= N) return;
  float s = ln2[(size_t)n * F + lane] * W3[lane] + ln2[(size_t)n * F + lane + 64] * W3[lane + 64];
  #pragma unroll
  for (int o = 1; o < 64; o <<= 1) s += __shfl_xor(s, o);
  if (lane == 0) {
    h3[n] = s;
    float d = dis[n];
    out[n] = s * d * d + b3[0];
  }
}

__global__ __launch_bounds__(256) void k_scatter3(const float* __restrict__ h3,
                                                  const int* __restrict__ src,
                                                  const int* __restrict__ dst,
                                                  const float* __restrict__ dis,
                                                  float* __restrict__ out, int E) {
  int e = blockIdx.x * 256 + threadIdx.x;
  if (e >= E) return;
  int s = src[e], d = dst[e];
  atomicAdd(&out[d], h3[s] * dis[s] * dis[d]);
}

// ---------------- launch ----------------
extern "C" void kernel_launch(void* const* d_in, const int* in_sizes, int n_in,
                              void* d_out, int out_size, void* d_ws, size_t ws_size,
                              hipStream_t stream) {
  const float* x     = (const float*)d_in[0];
  const int*   ei    = (const int*)d_in[1];   // edge_index, [2,E]; int32 per harness contract
  const float* W1    = (const float*)d_in[2];
  const float* b1    = (const float*)d_in[3];
  const float* W2    = (const float*)d_in[4];
  const float* b2    = (const float*)d_in[5];
  const float* W3    = (const float*)d_in[6];
  const float* b3    = (const float*)d_in[7];
  const float* gamma = (const float*)d_in[8];
  const float* beta  = (const float*)d_in[9];
  float* out = (float*)d_out;

  const int N = in_sizes[0] / F;   // 50000
  const int E = in_sizes[1] / 2;   // 600000
  const int* src = ei;
  const int* dst = ei + E;

  float* A   = (float*)d_ws;                // N*F : GEMM output h
  float* B   = A + (size_t)N * F;           // N*F : agg / ln buffer
  float* dis = B + (size_t)N * F;           // N   : deg -> deg_inv_sqrt
  float* h3  = dis + N;                     // N   : layer-3 pre-agg scalars

  hipMemsetAsync(dis, 0, (size_t)N * sizeof(float), stream);
  k_count_deg<<<(E + 255) / 256, 256, 0, stream>>>(dst, dis, E);
  k_dis<<<(N + 255) / 256, 256, 0, stream>>>(dis, N);

  const int gemm_blocks  = (N + 31) / 32;
  const int node_blocks  = (N + 3) / 4;
  const int f4_blocks    = (N * (F / 4) + 255) / 256;
  const int edge8_blocks = (E + 7) / 8;

  // layer 1
  k_gemm128<<<gemm_blocks, 256, 0, stream>>>(x, W1, A, N);
  k_init_agg<<<f4_blocks, 256, 0, stream>>>(A, dis, B, N);
  k_scatter<<<edge8_blocks, 256, 0, stream>>>(A, src, dst, dis, B, E);
  k_ln_relu<<<node_blocks, 256, 0, stream>>>(B, b1, gamma, beta, N);

  // layer 2
  k_gemm128<<<gemm_blocks, 256, 0, stream>>>(B, W2, A, N);
  k_init_agg<<<f4_blocks, 256, 0, stream>>>(A, dis, B, N);
  k_scatter<<<edge8_blocks, 256, 0, stream>>>(A, src, dst, dis, B, E);
  k_ln_relu<<<node_blocks, 256, 0, stream>>>(B, b2, gamma, beta, N);

  // layer 3
  k_layer3<<<node_blocks, 256, 0, stream>>>(B, W3, b3, dis, h3, out, N);
  k_scatter3<<<(E + 255) / 256, 256, 0, stream>>>(h3, src, dst, dis, out, E);
}

// Round 2
// 1644.891 us; speedup vs baseline: 2.1537x; 2.1537x over previous
//
#include <hip/hip_runtime.h>

#define F 128

// ================= CSR build =================
__global__ __launch_bounds__(256) void k_count(const int* __restrict__ dst,
                                               int* __restrict__ deg, int E) {
  int e = blockIdx.x * 256 + threadIdx.x;
  if (e < E) atomicAdd(&deg[dst[e]], 1);
}

__global__ __launch_bounds__(256) void k_dis(const int* __restrict__ deg,
                                             float* __restrict__ dis, int N) {
  int n = blockIdx.x * 256 + threadIdx.x;
  if (n < N) dis[n] = rsqrtf((float)deg[n] + 1.0f);
}

// pass 1: per-block inclusive scan of deg -> row_ptr[i+1]; block sum -> sums[b]
__global__ __launch_bounds__(256) void k_scan1(const int* __restrict__ deg,
                                               int* __restrict__ row_ptr,
                                               int* __restrict__ sums, int N) {
  int i = blockIdx.x * 256 + threadIdx.x;
  int lane = threadIdx.x & 63, wid = threadIdx.x >> 6;
  int v = (i < N) ? deg[i] : 0;
  #pragma unroll
  for (int o = 1; o < 64; o <<= 1) {
    int t = __shfl_up(v, o);
    if (lane >= o) v += t;
  }
  __shared__ int wsum[4];
  if (lane == 63) wsum[wid] = v;
  __syncthreads();
  if (threadIdx.x == 0) {
    int run = 0;
    #pragma unroll
    for (int w = 0; w < 4; ++w) { run += wsum[w]; wsum[w] = run; }
    sums[blockIdx.x] = run;
  }
  __syncthreads();
  if (wid > 0) v += wsum[wid - 1];
  if (i < N) row_ptr[i + 1] = v;
}

// pass 2: single block, exclusive scan of sums in place (nb <= 256)
__global__ __launch_bounds__(256) void k_scan2(int* __restrict__ sums, int nb) {
  int t = threadIdx.x;
  int lane = t & 63, wid = t >> 6;
  int orig = (t < nb) ? sums[t] : 0;
  int v = orig;
  #pragma unroll
  for (int o = 1; o < 64; o <<= 1) {
    int u = __shfl_up(v, o);
    if (lane >= o) v += u;
  }
  __shared__ int wsum[4];
  if (lane == 63) wsum[wid] = v;
  __syncthreads();
  if (t == 0) {
    int run = 0;
    #pragma unroll
    for (int w = 0; w < 4; ++w) { run += wsum[w]; wsum[w] = run; }
  }
  __syncthreads();
  if (wid > 0) v += wsum[wid - 1];
  if (t < nb) sums[t] = v - orig;   // exclusive
}

// pass 3: add block offsets; set row_ptr[0]; init cursor = row_ptr
__global__ __launch_bounds__(256) void k_scan3(int* __restrict__ row_ptr,
                                               const int* __restrict__ sums,
                                               int* __restrict__ cursor, int N) {
  int i = blockIdx.x * 256 + threadIdx.x;
  if (i == 0) row_ptr[0] = 0;
  if (i < N) {
    row_ptr[i + 1] += sums[blockIdx.x];
  }
}

__global__ __launch_bounds__(256) void k_cursor(const int* __restrict__ row_ptr,
                                                int* __restrict__ cursor, int N) {
  int i = blockIdx.x * 256 + threadIdx.x;
  if (i < N) cursor[i] = row_ptr[i];
}

__global__ __launch_bounds__(256) void k_fill(const int* __restrict__ src,
                                              const int* __restrict__ dst,
                                              int* __restrict__ cursor,
                                              int* __restrict__ csr_src, int E) {
  int e = blockIdx.x * 256 + threadIdx.x;
  if (e >= E) return;
  int pos = atomicAdd(&cursor[dst[e]], 1);
  csr_src[pos] = src[e];
}

// ================= GEMM: H[N,128] = X[N,128] @ W[128,128] =================
__global__ __launch_bounds__(256) void k_gemm128(const float* __restrict__ X,
                                                 const float* __restrict__ W,
                                                 float* __restrict__ H, int N) {
  __shared__ float xs[32][F];
  const int row0 = blockIdx.x * 32;
  const int tid = threadIdx.x;

  #pragma unroll
  for (int j = 0; j < 16; ++j) {
    int idx = tid + j * 256;
    int r = idx >> 7, c = idx & 127;
    int gr = row0 + r;
    xs[r][c] = (gr < N) ? X[(size_t)gr * F + c] : 0.0f;
  }
  __syncthreads();

  const int cg = (tid & 31) * 4;
  const int rg = (tid >> 5) * 4;
  float acc[4][4] = {};

  for (int k = 0; k < F; k += 4) {
    float4 xv[4];
    #pragma unroll
    for (int i = 0; i < 4; ++i) xv[i] = *(const float4*)&xs[rg + i][k];
    #pragma unroll
    for (int kk = 0; kk < 4; ++kk) {
      float4 wv = *(const float4*)&W[(k + kk) * F + cg];
      #pragma unroll
      for (int i = 0; i < 4; ++i) {
        float xi = (kk == 0) ? xv[i].x : (kk == 1) ? xv[i].y : (kk == 2) ? xv[i].z : xv[i].w;
        acc[i][0] += xi * wv.x;
        acc[i][1] += xi * wv.y;
        acc[i][2] += xi * wv.z;
        acc[i][3] += xi * wv.w;
      }
    }
  }

  #pragma unroll
  for (int i = 0; i < 4; ++i) {
    int gr = row0 + rg + i;
    if (gr < N)
      *(float4*)&H[(size_t)gr * F + cg] = make_float4(acc[i][0], acc[i][1], acc[i][2], acc[i][3]);
  }
}

// ======== fused gather-aggregate + bias + LayerNorm + ReLU, one wave/node ========
// agg = dis[n] * sum_e( H[src_e] * dis[src_e] ) + H[n]*dis[n]^2; then LN+ReLU.
__global__ __launch_bounds__(256) void k_agg_ln(const float* __restrict__ H,
                                                const int* __restrict__ row_ptr,
                                                const int* __restrict__ csr_src,
                                                const float* __restrict__ dis,
                                                const float* __restrict__ bias,
                                                const float* __restrict__ gamma,
                                                const float* __restrict__ beta,
                                                float* __restrict__ outB, int N) {
  int n = blockIdx.x * 4 + (threadIdx.x >> 6);
  int lane = threadIdx.x & 63;
  if (n >= N) return;
  float dn = dis[n];
  int beg = row_ptr[n], end = row_ptr[n + 1];
  float e0 = 0.0f, e1 = 0.0f;
  for (int e = beg; e < end; ++e) {
    int s = csr_src[e];
    float ws = dis[s];
    const float* hs = H + (size_t)s * F;
    e0 += hs[lane] * ws;
    e1 += hs[lane + 64] * ws;
  }
  const float* hn = H + (size_t)n * F;
  float v0 = e0 * dn + hn[lane] * dn * dn + bias[lane];
  float v1 = e1 * dn + hn[lane + 64] * dn * dn + bias[lane + 64];

  float s = v0 + v1;
  #pragma unroll
  for (int o = 1; o < 64; o <<= 1) s += __shfl_xor(s, o);
  float mu = s * (1.0f / F);
  float d0 = v0 - mu, d1 = v1 - mu;
  float sq = d0 * d0 + d1 * d1;
  #pragma unroll
  for (int o = 1; o < 64; o <<= 1) sq += __shfl_xor(sq, o);
  float inv = rsqrtf(sq * (1.0f / F) + 1e-5f);
  float o0 = d0 * inv * gamma[lane] + beta[lane];
  float o1 = d1 * inv * gamma[lane + 64] + beta[lane + 64];
  outB[(size_t)n * F + lane] = fmaxf(o0, 0.0f);
  outB[(size_t)n * F + lane + 64] = fmaxf(o1, 0.0f);
}

// ================= layer 3 =================
__global__ __launch_bounds__(256) void k_layer3(const float* __restrict__ ln2,
                                                const float* __restrict__ W3,
                                                float* __restrict__ h3, int N) {
  int n = blockIdx.x * 4 + (threadIdx.x >> 6);
  int lane = threadIdx.x & 63;
  if (n >= N) return;
  float s = ln2[(size_t)n * F + lane] * W3[lane] + ln2[(size_t)n * F + lane + 64] * W3[lane + 64];
  #pragma unroll
  for (int o = 1; o < 64; o <<= 1) s += __shfl_xor(s, o);
  if (lane == 0) h3[n] = s;
}

__global__ __launch_bounds__(256) void k_out(const float* __restrict__ h3,
                                             const int* __restrict__ row_ptr,
                                             const int* __restrict__ csr_src,
                                             const float* __restrict__ dis,
                                             const float* __restrict__ b3,
                                             float* __restrict__ out, int N) {
  int n = blockIdx.x * 4 + (threadIdx.x >> 6);
  int lane = threadIdx.x & 63;
  if (n >= N) return;
  float dn = dis[n];
  int beg = row_ptr[n], end = row_ptr[n + 1];
  float s = 0.0f;
  for (int e = beg + lane; e < end; e += 64) {
    int src = csr_src[e];
    s += h3[src] * dis[src];
  }
  #pragma unroll
  for (int o = 1; o < 64; o <<= 1) s += __shfl_xor(s, o);
  if (lane == 0) out[n] = s * dn + h3[n] * dn * dn + b3[0];
}

// ================= launch =================
extern "C" void kernel_launch(void* const* d_in, const int* in_sizes, int n_in,
                              void* d_out, int out_size, void* d_ws, size_t ws_size,
                              hipStream_t stream) {
  const float* x     = (const float*)d_in[0];
  const int*   ei    = (const int*)d_in[1];
  const float* W1    = (const float*)d_in[2];
  const float* b1    = (const float*)d_in[3];
  const float* W2    = (const float*)d_in[4];
  const float* b2    = (const float*)d_in[5];
  const float* W3    = (const float*)d_in[6];
  const float* b3    = (const float*)d_in[7];
  const float* gamma = (const float*)d_in[8];
  const float* beta  = (const float*)d_in[9];
  float* out = (float*)d_out;

  const int N = in_sizes[0] / F;   // 50000
  const int E = in_sizes[1] / 2;   // 600000
  const int* src = ei;
  const int* dst = ei + E;

  float* A       = (float*)d_ws;            // N*F
  float* B       = A + (size_t)N * F;       // N*F
  float* dis     = B + (size_t)N * F;       // N
  float* h3      = dis + N;                 // N
  int*   deg     = (int*)(h3 + N);          // N (aliased as cursor after k_dis/scan)
  int*   row_ptr = deg + N;                 // N+1
  int*   sums    = row_ptr + N + 1;         // <=256
  int*   csr_src = sums + 256;              // E

  const int eb = (E + 255) / 256;
  const int nb = (N + 255) / 256;           // 196 blocks (<=256 for scan2)
  const int node_blocks = (N + 3) / 4;
  const int gemm_blocks = (N + 31) / 32;

  // ---- CSR build ----
  hipMemsetAsync(deg, 0, (size_t)N * sizeof(int), stream);
  k_count<<<eb, 256, 0, stream>>>(dst, deg, E);
  k_dis<<<nb, 256, 0, stream>>>(deg, dis, N);
  k_scan1<<<nb, 256, 0, stream>>>(deg, row_ptr, sums, N);
  k_scan2<<<1, 256, 0, stream>>>(sums, nb);
  k_scan3<<<nb, 256, 0, stream>>>(row_ptr, sums, deg, N);
  k_cursor<<<nb, 256, 0, stream>>>(row_ptr, deg, N);      // cursor aliases deg
  k_fill<<<eb, 256, 0, stream>>>(src, dst, deg, csr_src, E);

  // ---- layer 1 ----
  k_gemm128<<<gemm_blocks, 256, 0, stream>>>(x, W1, A, N);
  k_agg_ln<<<node_blocks, 256, 0, stream>>>(A, row_ptr, csr_src, dis, b1, gamma, beta, B, N);

  // ---- layer 2 ----
  k_gemm128<<<gemm_blocks, 256, 0, stream>>>(B, W2, A, N);
  k_agg_ln<<<node_blocks, 256, 0, stream>>>(A, row_ptr, csr_src, dis, b2, gamma, beta, B, N);

  // ---- layer 3 ----
  k_layer3<<<node_blocks, 256, 0, stream>>>(B, W3, h3, N);
  k_out<<<node_blocks, 256, 0, stream>>>(h3, row_ptr, csr_src, dis, b3, out, N);
}

// Round 3
// 377.935 us; speedup vs baseline: 9.3735x; 4.3523x over previous
//
#include <hip/hip_runtime.h>

#define F 128

// ================= CSR build =================
__global__ __launch_bounds__(256) void k_count(const int* __restrict__ dst,
                                               int* __restrict__ deg, int E) {
  int e = blockIdx.x * 256 + threadIdx.x;
  if (e < E) atomicAdd(&deg[dst[e]], 1);
}

__global__ __launch_bounds__(256) void k_dis(const int* __restrict__ deg,
                                             float* __restrict__ dis, int N) {
  int n = blockIdx.x * 256 + threadIdx.x;
  if (n < N) dis[n] = rsqrtf((float)deg[n] + 1.0f);
}

// pass 1: per-block inclusive scan of deg -> row_ptr[i+1]; block sum -> sums[b]
__global__ __launch_bounds__(256) void k_scan1(const int* __restrict__ deg,
                                               int* __restrict__ row_ptr,
                                               int* __restrict__ sums, int N) {
  int i = blockIdx.x * 256 + threadIdx.x;
  int lane = threadIdx.x & 63, wid = threadIdx.x >> 6;
  int v = (i < N) ? deg[i] : 0;
  #pragma unroll
  for (int o = 1; o < 64; o <<= 1) {
    int t = __shfl_up(v, o);
    if (lane >= o) v += t;
  }
  __shared__ int wsum[4];
  if (lane == 63) wsum[wid] = v;
  __syncthreads();
  if (threadIdx.x == 0) {
    int run = 0;
    #pragma unroll
    for (int w = 0; w < 4; ++w) { run += wsum[w]; wsum[w] = run; }
    sums[blockIdx.x] = run;
  }
  __syncthreads();
  if (wid > 0) v += wsum[wid - 1];
  if (i < N) row_ptr[i + 1] = v;
}

// pass 2: single block, exclusive scan of sums in place (nb <= 256)
__global__ __launch_bounds__(256) void k_scan2(int* __restrict__ sums, int nb) {
  int t = threadIdx.x;
  int lane = t & 63, wid = t >> 6;
  int orig = (t < nb) ? sums[t] : 0;
  int v = orig;
  #pragma unroll
  for (int o = 1; o < 64; o <<= 1) {
    int u = __shfl_up(v, o);
    if (lane >= o) v += u;
  }
  __shared__ int wsum[4];
  if (lane == 63) wsum[wid] = v;
  __syncthreads();
  if (t == 0) {
    int run = 0;
    #pragma unroll
    for (int w = 0; w < 4; ++w) { run += wsum[w]; wsum[w] = run; }
  }
  __syncthreads();
  if (wid > 0) v += wsum[wid - 1];
  if (t < nb) sums[t] = v - orig;   // exclusive
}

// pass 3: add block offsets; set row_ptr[0]
__global__ __launch_bounds__(256) void k_scan3(int* __restrict__ row_ptr,
                                               const int* __restrict__ sums, int N) {
  int i = blockIdx.x * 256 + threadIdx.x;
  if (i == 0) row_ptr[0] = 0;
  if (i < N) row_ptr[i + 1] += sums[blockIdx.x];
}

__global__ __launch_bounds__(256) void k_cursor(const int* __restrict__ row_ptr,
                                                int* __restrict__ cursor, int N) {
  int i = blockIdx.x * 256 + threadIdx.x;
  if (i < N) cursor[i] = row_ptr[i];
}

__global__ __launch_bounds__(256) void k_fill(const int* __restrict__ src,
                                              const int* __restrict__ dst,
                                              int* __restrict__ cursor,
                                              int* __restrict__ csr_src, int E) {
  int e = blockIdx.x * 256 + threadIdx.x;
  if (e >= E) return;
  int pos = atomicAdd(&cursor[dst[e]], 1);
  csr_src[pos] = src[e];
}

// ================= GEMM: H[N,128] = X[N,128] @ W[128,128] =================
// 32-row tile in LDS, thread = 4 rows x 4 cols. k-loop unroll capped at 2 to
// keep live set ~50 VGPRs (full unroll hoisted all W loads -> 256 VGPR + spill).
__global__ __launch_bounds__(256) void k_gemm128(const float* __restrict__ X,
                                                 const float* __restrict__ W,
                                                 float* __restrict__ H, int N) {
  __shared__ float xs[32][F];
  const int row0 = blockIdx.x * 32;
  const int tid = threadIdx.x;

  // stage 32x128 floats = 1024 float4, 4 per thread, fully coalesced
  #pragma unroll
  for (int j = 0; j < 4; ++j) {
    int idx4 = tid + j * 256;           // float4 index into xs
    int r = idx4 >> 5, cc = idx4 & 31;  // 32 float4 per row
    int gr = row0 + r;
    ((float4*)xs)[idx4] = (gr < N) ? ((const float4*)X)[(size_t)gr * 32 + cc]
                                   : make_float4(0.f, 0.f, 0.f, 0.f);
  }
  __syncthreads();

  const int cg = (tid & 31) * 4;
  const int rg = (tid >> 5) * 4;
  float acc[4][4] = {};

  #pragma unroll 2
  for (int k = 0; k < F; k += 4) {
    float4 xv[4];
    #pragma unroll
    for (int i = 0; i < 4; ++i) xv[i] = *(const float4*)&xs[rg + i][k];
    #pragma unroll
    for (int kk = 0; kk < 4; ++kk) {
      float4 wv = *(const float4*)&W[(k + kk) * F + cg];
      #pragma unroll
      for (int i = 0; i < 4; ++i) {
        float xi = (kk == 0) ? xv[i].x : (kk == 1) ? xv[i].y : (kk == 2) ? xv[i].z : xv[i].w;
        acc[i][0] += xi * wv.x;
        acc[i][1] += xi * wv.y;
        acc[i][2] += xi * wv.z;
        acc[i][3] += xi * wv.w;
      }
    }
  }

  #pragma unroll
  for (int i = 0; i < 4; ++i) {
    int gr = row0 + rg + i;
    if (gr < N)
      *(float4*)&H[(size_t)gr * F + cg] = make_float4(acc[i][0], acc[i][1], acc[i][2], acc[i][3]);
  }
}

// ======== fused gather-aggregate + bias + LayerNorm + ReLU, one wave/node ========
__global__ __launch_bounds__(256) void k_agg_ln(const float* __restrict__ H,
                                                const int* __restrict__ row_ptr,
                                                const int* __restrict__ csr_src,
                                                const float* __restrict__ dis,
                                                const float* __restrict__ bias,
                                                const float* __restrict__ gamma,
                                                const float* __restrict__ beta,
                                                float* __restrict__ outB, int N) {
  int n = blockIdx.x * 4 + (threadIdx.x >> 6);
  int lane = threadIdx.x & 63;
  if (n >= N) return;
  float dn = dis[n];
  int beg = row_ptr[n], end = row_ptr[n + 1];
  float e0 = 0.0f, e1 = 0.0f;
  for (int e = beg; e < end; ++e) {
    int s = csr_src[e];
    float ws = dis[s];
    const float* hs = H + (size_t)s * F;
    e0 += hs[lane] * ws;
    e1 += hs[lane + 64] * ws;
  }
  const float* hn = H + (size_t)n * F;
  float v0 = e0 * dn + hn[lane] * dn * dn + bias[lane];
  float v1 = e1 * dn + hn[lane + 64] * dn * dn + bias[lane + 64];

  float s = v0 + v1;
  #pragma unroll
  for (int o = 1; o < 64; o <<= 1) s += __shfl_xor(s, o);
  float mu = s * (1.0f / F);
  float d0 = v0 - mu, d1 = v1 - mu;
  float sq = d0 * d0 + d1 * d1;
  #pragma unroll
  for (int o = 1; o < 64; o <<= 1) sq += __shfl_xor(sq, o);
  float inv = rsqrtf(sq * (1.0f / F) + 1e-5f);
  float o0 = d0 * inv * gamma[lane] + beta[lane];
  float o1 = d1 * inv * gamma[lane + 64] + beta[lane + 64];
  outB[(size_t)n * F + lane] = fmaxf(o0, 0.0f);
  outB[(size_t)n * F + lane + 64] = fmaxf(o1, 0.0f);
}

// ================= layer 3 =================
__global__ __launch_bounds__(256) void k_layer3(const float* __restrict__ ln2,
                                                const float* __restrict__ W3,
                                                float* __restrict__ h3, int N) {
  int n = blockIdx.x * 4 + (threadIdx.x >> 6);
  int lane = threadIdx.x & 63;
  if (n >= N) return;
  float s = ln2[(size_t)n * F + lane] * W3[lane] + ln2[(size_t)n * F + lane + 64] * W3[lane + 64];
  #pragma unroll
  for (int o = 1; o < 64; o <<= 1) s += __shfl_xor(s, o);
  if (lane == 0) h3[n] = s;
}

__global__ __launch_bounds__(256) void k_out(const float* __restrict__ h3,
                                             const int* __restrict__ row_ptr,
                                             const int* __restrict__ csr_src,
                                             const float* __restrict__ dis,
                                             const float* __restrict__ b3,
                                             float* __restrict__ out, int N) {
  int n = blockIdx.x * 4 + (threadIdx.x >> 6);
  int lane = threadIdx.x & 63;
  if (n >= N) return;
  float dn = dis[n];
  int beg = row_ptr[n], end = row_ptr[n + 1];
  float s = 0.0f;
  for (int e = beg + lane; e < end; e += 64) {
    int src = csr_src[e];
    s += h3[src] * dis[src];
  }
  #pragma unroll
  for (int o = 1; o < 64; o <<= 1) s += __shfl_xor(s, o);
  if (lane == 0) out[n] = s * dn + h3[n] * dn * dn + b3[0];
}

// ================= launch =================
extern "C" void kernel_launch(void* const* d_in, const int* in_sizes, int n_in,
                              void* d_out, int out_size, void* d_ws, size_t ws_size,
                              hipStream_t stream) {
  const float* x     = (const float*)d_in[0];
  const int*   ei    = (const int*)d_in[1];
  const float* W1    = (const float*)d_in[2];
  const float* b1    = (const float*)d_in[3];
  const float* W2    = (const float*)d_in[4];
  const float* b2    = (const float*)d_in[5];
  const float* W3    = (const float*)d_in[6];
  const float* b3    = (const float*)d_in[7];
  const float* gamma = (const float*)d_in[8];
  const float* beta  = (const float*)d_in[9];
  float* out = (float*)d_out;

  const int N = in_sizes[0] / F;   // 50000
  const int E = in_sizes[1] / 2;   // 600000
  const int* src = ei;
  const int* dst = ei + E;

  float* A       = (float*)d_ws;            // N*F
  float* B       = A + (size_t)N * F;       // N*F
  float* dis     = B + (size_t)N * F;       // N
  float* h3      = dis + N;                 // N
  int*   deg     = (int*)(h3 + N);          // N (reused as cursor)
  int*   row_ptr = deg + N;                 // N+1
  int*   sums    = row_ptr + N + 1;         // <=256
  int*   csr_src = sums + 256;              // E

  const int eb = (E + 255) / 256;
  const int nb = (N + 255) / 256;           // 196 blocks (<=256 for scan2)
  const int node_blocks = (N + 3) / 4;
  const int gemm_blocks = (N + 31) / 32;

  // ---- CSR build ----
  hipMemsetAsync(deg, 0, (size_t)N * sizeof(int), stream);
  k_count<<<eb, 256, 0, stream>>>(dst, deg, E);
  k_dis<<<nb, 256, 0, stream>>>(deg, dis, N);
  k_scan1<<<nb, 256, 0, stream>>>(deg, row_ptr, sums, N);
  k_scan2<<<1, 256, 0, stream>>>(sums, nb);
  k_scan3<<<nb, 256, 0, stream>>>(row_ptr, sums, N);
  k_cursor<<<nb, 256, 0, stream>>>(row_ptr, deg, N);      // cursor aliases deg
  k_fill<<<eb, 256, 0, stream>>>(src, dst, deg, csr_src, E);

  // ---- layer 1 ----
  k_gemm128<<<gemm_blocks, 256, 0, stream>>>(x, W1, A, N);
  k_agg_ln<<<node_blocks, 256, 0, stream>>>(A, row_ptr, csr_src, dis, b1, gamma, beta, B, N);

  // ---- layer 2 ----
  k_gemm128<<<gemm_blocks, 256, 0, stream>>>(B, W2, A, N);
  k_agg_ln<<<node_blocks, 256, 0, stream>>>(A, row_ptr, csr_src, dis, b2, gamma, beta, B, N);

  // ---- layer 3 ----
  k_layer3<<<node_blocks, 256, 0, stream>>>(B, W3, h3, N);
  k_out<<<node_blocks, 256, 0, stream>>>(h3, row_ptr, csr_src, dis, b3, out, N);
}

// Round 4
// 297.790 us; speedup vs baseline: 11.8962x; 1.2691x over previous
//
#include <hip/hip_runtime.h>

#define F 128

typedef __attribute__((ext_vector_type(8))) __bf16 bf16x8;
typedef __attribute__((ext_vector_type(4))) float f32x4;

__device__ __forceinline__ float bflo(unsigned u) { return __uint_as_float(u << 16); }
__device__ __forceinline__ float bfhi(unsigned u) { return __uint_as_float(u & 0xffff0000u); }
__device__ __forceinline__ unsigned short bfbits(float f) {
  __bf16 h = (__bf16)f;
  union { __bf16 b; unsigned short s; } v; v.b = h; return v.s;
}
__device__ __forceinline__ unsigned packbf(float a, float b) {
  return (unsigned)bfbits(a) | ((unsigned)bfbits(b) << 16);
}

// ================= CSR build =================
__global__ __launch_bounds__(256) void k_count(const int* __restrict__ dst,
                                               int* __restrict__ deg, int E) {
  int e = blockIdx.x * 256 + threadIdx.x;
  if (e < E) atomicAdd(&deg[dst[e]], 1);
}

__global__ __launch_bounds__(256) void k_dis(const int* __restrict__ deg,
                                             float* __restrict__ dis, int N) {
  int n = blockIdx.x * 256 + threadIdx.x;
  if (n < N) dis[n] = rsqrtf((float)deg[n] + 1.0f);
}

__global__ __launch_bounds__(256) void k_scan1(const int* __restrict__ deg,
                                               int* __restrict__ row_ptr,
                                               int* __restrict__ sums, int N) {
  int i = blockIdx.x * 256 + threadIdx.x;
  int lane = threadIdx.x & 63, wid = threadIdx.x >> 6;
  int v = (i < N) ? deg[i] : 0;
  #pragma unroll
  for (int o = 1; o < 64; o <<= 1) {
    int t = __shfl_up(v, o);
    if (lane >= o) v += t;
  }
  __shared__ int wsum[4];
  if (lane == 63) wsum[wid] = v;
  __syncthreads();
  if (threadIdx.x == 0) {
    int run = 0;
    #pragma unroll
    for (int w = 0; w < 4; ++w) { run += wsum[w]; wsum[w] = run; }
    sums[blockIdx.x] = run;
  }
  __syncthreads();
  if (wid > 0) v += wsum[wid - 1];
  if (i < N) row_ptr[i + 1] = v;
}

__global__ __launch_bounds__(256) void k_scan2(int* __restrict__ sums, int nb) {
  int t = threadIdx.x;
  int lane = t & 63, wid = t >> 6;
  int orig = (t < nb) ? sums[t] : 0;
  int v = orig;
  #pragma unroll
  for (int o = 1; o < 64; o <<= 1) {
    int u = __shfl_up(v, o);
    if (lane >= o) v += u;
  }
  __shared__ int wsum[4];
  if (lane == 63) wsum[wid] = v;
  __syncthreads();
  if (t == 0) {
    int run = 0;
    #pragma unroll
    for (int w = 0; w < 4; ++w) { run += wsum[w]; wsum[w] = run; }
  }
  __syncthreads();
  if (wid > 0) v += wsum[wid - 1];
  if (t < nb) sums[t] = v - orig;
}

__global__ __launch_bounds__(256) void k_scan3(int* __restrict__ row_ptr,
                                               const int* __restrict__ sums, int N) {
  int i = blockIdx.x * 256 + threadIdx.x;
  if (i == 0) row_ptr[0] = 0;
  if (i < N) row_ptr[i + 1] += sums[blockIdx.x];
}

__global__ __launch_bounds__(256) void k_cursor(const int* __restrict__ row_ptr,
                                                int* __restrict__ cursor, int N) {
  int i = blockIdx.x * 256 + threadIdx.x;
  if (i < N) cursor[i] = row_ptr[i];
}

// csr entry = (src, bits(dis[src])) so the hot gather loop gets index+weight in one 8B load
__global__ __launch_bounds__(256) void k_fill(const int* __restrict__ src,
                                              const int* __restrict__ dst,
                                              const float* __restrict__ dis,
                                              int* __restrict__ cursor,
                                              int2* __restrict__ csr, int E) {
  int e = blockIdx.x * 256 + threadIdx.x;
  if (e >= E) return;
  int s = src[e];
  int pos = atomicAdd(&cursor[dst[e]], 1);
  csr[pos] = make_int2(s, __float_as_int(dis[s]));
}

// ================= fp32 -> bf16 cast (x input) =================
__global__ __launch_bounds__(256) void k_cast(const float* __restrict__ X,
                                              unsigned* __restrict__ Xb, int total2) {
  int i = blockIdx.x * 256 + threadIdx.x;
  if (i >= total2) return;
  float2 v = ((const float2*)X)[i];
  Xb[i] = packbf(v.x, v.y);
}

// ================= pack W[128,128] into B-fragment order =================
// frag (c=col-tile 0..7, t=k-iter 0..3, lane 0..63): 8 bf16, j-th = W[t*32+(lane>>4)*8+j][c*16+(lane&15)]
__global__ __launch_bounds__(256) void k_pack(const float* __restrict__ W,
                                              unsigned short* __restrict__ Wp) {
  int idx = blockIdx.x * 256 + threadIdx.x;   // 2048 frags
  if (idx >= 2048) return;
  int l = idx & 63, ct = idx >> 6, t = ct & 3, c = ct >> 2;
  int q = l >> 4, m = l & 15;
  #pragma unroll
  for (int j = 0; j < 8; ++j)
    Wp[idx * 8 + j] = bfbits(W[(t * 32 + q * 8 + j) * F + c * 16 + m]);
}

// ================= MFMA GEMM: H[N,128] = A[N,128] @ W, bf16 in/out =================
// one wave per 16 rows; A frags direct from global; W frags from packed array (L1-hot)
__global__ __launch_bounds__(256) void k_gemm(const __bf16* __restrict__ A,
                                              const __bf16* __restrict__ Wp,
                                              unsigned short* __restrict__ H, int nTiles) {
  int gid = blockIdx.x * 4 + (threadIdx.x >> 6);
  if (gid >= nTiles) return;
  int lane = threadIdx.x & 63, m = lane & 15, q = lane >> 4;
  const int row0 = gid * 16;
  f32x4 acc[8];
  #pragma unroll
  for (int c = 0; c < 8; ++c) acc[c] = (f32x4){0.f, 0.f, 0.f, 0.f};

  const __bf16* arow = A + (size_t)(row0 + m) * F + q * 8;
  #pragma unroll
  for (int t = 0; t < 4; ++t) {
    bf16x8 af = *(const bf16x8*)(arow + t * 32);
    #pragma unroll
    for (int c = 0; c < 8; ++c) {
      bf16x8 bfr = *(const bf16x8*)(Wp + ((size_t)(c * 4 + t) * 64 + lane) * 8);
      acc[c] = __builtin_amdgcn_mfma_f32_16x16x32_bf16(af, bfr, acc[c], 0, 0, 0);
    }
  }
  #pragma unroll
  for (int c = 0; c < 8; ++c) {
    #pragma unroll
    for (int r = 0; r < 4; ++r) {
      int row = row0 + q * 4 + r;
      H[(size_t)row * F + c * 16 + m] = bfbits(acc[c][r]);
    }
  }
}

// ===== fused gather-aggregate + bias + LayerNorm + ReLU; bf16 rows, one wave/node =====
// lane covers features {2*lane, 2*lane+1}
__global__ __launch_bounds__(256) void k_agg_ln(const unsigned* __restrict__ Hb,
                                                const int* __restrict__ row_ptr,
                                                const int2* __restrict__ csr,
                                                const float* __restrict__ dis,
                                                const float* __restrict__ bias,
                                                const float* __restrict__ gamma,
                                                const float* __restrict__ beta,
                                                unsigned* __restrict__ Bb, int N) {
  int n = blockIdx.x * 4 + (threadIdx.x >> 6);
  int lane = threadIdx.x & 63;
  if (n >= N) return;
  float dn = dis[n];
  int e = row_ptr[n], end = row_ptr[n + 1];
  float e0 = 0.f, e1 = 0.f, f0 = 0.f, f1 = 0.f;
  for (; e + 2 <= end; e += 2) {
    int2 c0 = csr[e], c1 = csr[e + 1];
    unsigned u0 = Hb[(size_t)c0.x * 64 + lane];
    unsigned u1 = Hb[(size_t)c1.x * 64 + lane];
    float w0 = __int_as_float(c0.y), w1 = __int_as_float(c1.y);
    e0 = fmaf(bflo(u0), w0, e0); e1 = fmaf(bfhi(u0), w0, e1);
    f0 = fmaf(bflo(u1), w1, f0); f1 = fmaf(bfhi(u1), w1, f1);
  }
  if (e < end) {
    int2 c0 = csr[e];
    unsigned u0 = Hb[(size_t)c0.x * 64 + lane];
    float w0 = __int_as_float(c0.y);
    e0 = fmaf(bflo(u0), w0, e0); e1 = fmaf(bfhi(u0), w0, e1);
  }
  e0 += f0; e1 += f1;

  unsigned su = Hb[(size_t)n * 64 + lane];
  float2 bi = ((const float2*)bias)[lane];
  float v0 = e0 * dn + bflo(su) * dn * dn + bi.x;
  float v1 = e1 * dn + bfhi(su) * dn * dn + bi.y;

  float s = v0 + v1;
  #pragma unroll
  for (int o = 1; o < 64; o <<= 1) s += __shfl_xor(s, o);
  float mu = s * (1.0f / F);
  float d0 = v0 - mu, d1 = v1 - mu;
  float sq = d0 * d0 + d1 * d1;
  #pragma unroll
  for (int o = 1; o < 64; o <<= 1) sq += __shfl_xor(sq, o);
  float inv = rsqrtf(sq * (1.0f / F) + 1e-5f);
  float2 ga = ((const float2*)gamma)[lane];
  float2 be = ((const float2*)beta)[lane];
  float o0 = d0 * inv * ga.x + be.x;
  float o1 = d1 * inv * ga.y + be.y;
  Bb[(size_t)n * 64 + lane] = packbf(fmaxf(o0, 0.f), fmaxf(o1, 0.f));
}

// ================= layer 3 =================
__global__ __launch_bounds__(256) void k_layer3(const unsigned* __restrict__ Bb,
                                                const float* __restrict__ W3,
                                                float* __restrict__ h3, int N) {
  int n = blockIdx.x * 4 + (threadIdx.x >> 6);
  int lane = threadIdx.x & 63;
  if (n >= N) return;
  unsigned u = Bb[(size_t)n * 64 + lane];
  float2 w = ((const float2*)W3)[lane];
  float s = bflo(u) * w.x + bfhi(u) * w.y;
  #pragma unroll
  for (int o = 1; o < 64; o <<= 1) s += __shfl_xor(s, o);
  if (lane == 0) h3[n] = s;
}

__global__ __launch_bounds__(256) void k_out(const float* __restrict__ h3,
                                             const int* __restrict__ row_ptr,
                                             const int2* __restrict__ csr,
                                             const float* __restrict__ dis,
                                             const float* __restrict__ b3,
                                             float* __restrict__ out, int N) {
  int n = blockIdx.x * 4 + (threadIdx.x >> 6);
  int lane = threadIdx.x & 63;
  if (n >= N) return;
  float dn = dis[n];
  int beg = row_ptr[n], end = row_ptr[n + 1];
  float s = 0.0f;
  for (int e = beg + lane; e < end; e += 64) {
    int2 c = csr[e];
    s += h3[c.x] * __int_as_float(c.y);
  }
  #pragma unroll
  for (int o = 1; o < 64; o <<= 1) s += __shfl_xor(s, o);
  if (lane == 0) out[n] = s * dn + h3[n] * dn * dn + b3[0];
}

// ================= launch =================
extern "C" void kernel_launch(void* const* d_in, const int* in_sizes, int n_in,
                              void* d_out, int out_size, void* d_ws, size_t ws_size,
                              hipStream_t stream) {
  const float* x     = (const float*)d_in[0];
  const int*   ei    = (const int*)d_in[1];
  const float* W1    = (const float*)d_in[2];
  const float* b1    = (const float*)d_in[3];
  const float* W2    = (const float*)d_in[4];
  const float* b2    = (const float*)d_in[5];
  const float* W3    = (const float*)d_in[6];
  const float* b3    = (const float*)d_in[7];
  const float* gamma = (const float*)d_in[8];
  const float* beta  = (const float*)d_in[9];
  float* out = (float*)d_out;

  const int N = in_sizes[0] / F;   // 50000
  const int E = in_sizes[1] / 2;   // 600000
  const int* src = ei;
  const int* dst = ei + E;

  // ws layout (16B-aligned chunks)
  unsigned*       Hb      = (unsigned*)d_ws;            // N*64 uints (bf16 rows)
  unsigned*       Bbuf    = Hb + (size_t)N * 64;        // N*64
  unsigned*       Xb      = Bbuf + (size_t)N * 64;      // N*64
  unsigned short* Wp1     = (unsigned short*)(Xb + (size_t)N * 64);   // 16384
  unsigned short* Wp2     = Wp1 + 16384;                // 16384
  int2*           csr     = (int2*)(Wp2 + 16384);       // E
  float*          dis     = (float*)(csr + E);          // N
  float*          h3      = dis + N;                    // N
  int*            deg     = (int*)(h3 + N);             // N (reused as cursor)
  int*            row_ptr = deg + N;                    // N+1
  int*            sums    = row_ptr + N + 1;            // <=256

  const int eb = (E + 255) / 256;
  const int nb = (N + 255) / 256;           // 196 (<=256 for scan2)
  const int node_blocks = (N + 3) / 4;
  const int nTiles = (N + 15) / 16;         // 3125 (N divisible by 16)
  const int gemm_blocks = (nTiles + 3) / 4;

  // ---- CSR build + dis ----
  hipMemsetAsync(deg, 0, (size_t)N * sizeof(int), stream);
  k_count<<<eb, 256, 0, stream>>>(dst, deg, E);
  k_dis<<<nb, 256, 0, stream>>>(deg, dis, N);
  k_scan1<<<nb, 256, 0, stream>>>(deg, row_ptr, sums, N);
  k_scan2<<<1, 256, 0, stream>>>(sums, nb);
  k_scan3<<<nb, 256, 0, stream>>>(row_ptr, sums, N);
  k_cursor<<<nb, 256, 0, stream>>>(row_ptr, deg, N);
  k_fill<<<eb, 256, 0, stream>>>(src, dst, dis, deg, csr, E);

  // ---- precompute bf16 operands ----
  k_cast<<<(N * 64 + 255) / 256, 256, 0, stream>>>(x, Xb, N * 64);
  k_pack<<<8, 256, 0, stream>>>(W1, Wp1);
  k_pack<<<8, 256, 0, stream>>>(W2, Wp2);

  // ---- layer 1 ----
  k_gemm<<<gemm_blocks, 256, 0, stream>>>((const __bf16*)Xb, (const __bf16*)Wp1,
                                          (unsigned short*)Hb, nTiles);
  k_agg_ln<<<node_blocks, 256, 0, stream>>>(Hb, row_ptr, csr, dis, b1, gamma, beta, Bbuf, N);

  // ---- layer 2 ----
  k_gemm<<<gemm_blocks, 256, 0, stream>>>((const __bf16*)Bbuf, (const __bf16*)Wp2,
                                          (unsigned short*)Hb, nTiles);
  k_agg_ln<<<node_blocks, 256, 0, stream>>>(Hb, row_ptr, csr, dis, b2, gamma, beta, Bbuf, N);

  // ---- layer 3 ----
  k_layer3<<<node_blocks, 256, 0, stream>>>(Bbuf, W3, h3, N);
  k_out<<<node_blocks, 256, 0, stream>>>(h3, row_ptr, csr, dis, b3, out, N);
}

// Round 5
// 268.943 us; speedup vs baseline: 13.1722x; 1.1073x over previous
//
#include <hip/hip_runtime.h>

#define F 128

typedef __attribute__((ext_vector_type(8))) __bf16 bf16x8;
typedef __attribute__((ext_vector_type(4))) float f32x4;

__device__ __forceinline__ float bflo(unsigned u) { return __uint_as_float(u << 16); }
__device__ __forceinline__ float bfhi(unsigned u) { return __uint_as_float(u & 0xffff0000u); }
__device__ __forceinline__ unsigned short bfbits(float f) {
  __bf16 h = (__bf16)f;
  union { __bf16 b; unsigned short s; } v; v.b = h; return v.s;
}
__device__ __forceinline__ unsigned packbf(float a, float b) {
  return (unsigned)bfbits(a) | ((unsigned)bfbits(b) << 16);
}

// ================= CSR build =================
__global__ __launch_bounds__(256) void k_count(const int* __restrict__ dst,
                                               int* __restrict__ deg, int E) {
  int e = blockIdx.x * 256 + threadIdx.x;
  if (e < E) atomicAdd(&deg[dst[e]], 1);
}

// scan pass 1 + dis = rsqrt(deg+1) fused
__global__ __launch_bounds__(256) void k_scan1(const int* __restrict__ deg,
                                               int* __restrict__ row_ptr,
                                               int* __restrict__ sums,
                                               float* __restrict__ dis, int N) {
  int i = blockIdx.x * 256 + threadIdx.x;
  int lane = threadIdx.x & 63, wid = threadIdx.x >> 6;
  int d = (i < N) ? deg[i] : 0;
  if (i < N) dis[i] = rsqrtf((float)d + 1.0f);
  int v = d;
  #pragma unroll
  for (int o = 1; o < 64; o <<= 1) {
    int t = __shfl_up(v, o);
    if (lane >= o) v += t;
  }
  __shared__ int wsum[4];
  if (lane == 63) wsum[wid] = v;
  __syncthreads();
  if (threadIdx.x == 0) {
    int run = 0;
    #pragma unroll
    for (int w = 0; w < 4; ++w) { run += wsum[w]; wsum[w] = run; }
    sums[blockIdx.x] = run;
  }
  __syncthreads();
  if (wid > 0) v += wsum[wid - 1];
  if (i < N) row_ptr[i + 1] = v;
}

__global__ __launch_bounds__(256) void k_scan2(int* __restrict__ sums, int nb) {
  int t = threadIdx.x;
  int lane = t & 63, wid = t >> 6;
  int orig = (t < nb) ? sums[t] : 0;
  int v = orig;
  #pragma unroll
  for (int o = 1; o < 64; o <<= 1) {
    int u = __shfl_up(v, o);
    if (lane >= o) v += u;
  }
  __shared__ int wsum[4];
  if (lane == 63) wsum[wid] = v;
  __syncthreads();
  if (t == 0) {
    int run = 0;
    #pragma unroll
    for (int w = 0; w < 4; ++w) { run += wsum[w]; wsum[w] = run; }
  }
  __syncthreads();
  if (wid > 0) v += wsum[wid - 1];
  if (t < nb) sums[t] = v - orig;
}

__global__ __launch_bounds__(256) void k_scan3(int* __restrict__ row_ptr,
                                               const int* __restrict__ sums, int N) {
  int i = blockIdx.x * 256 + threadIdx.x;
  if (i == 0) row_ptr[0] = 0;
  if (i < N) row_ptr[i + 1] += sums[blockIdx.x];
}

// k_fill bumps row_ptr[dst] directly (cursor == segment start pre-fill).
// POST-FILL convention: segment of node n = [ n? row_ptr[n-1]:0 , row_ptr[n] ).
__global__ __launch_bounds__(256) void k_fill(const int* __restrict__ src,
                                              const int* __restrict__ dst,
                                              const float* __restrict__ dis,
                                              int* __restrict__ row_ptr,
                                              int2* __restrict__ csr, int E) {
  int e = blockIdx.x * 256 + threadIdx.x;
  if (e >= E) return;
  int s = src[e];
  int pos = atomicAdd(&row_ptr[dst[e]], 1);
  csr[pos] = make_int2(s, __float_as_int(dis[s]));
}

// ================= pack W[128,128] into B-fragment order =================
__global__ __launch_bounds__(256) void k_pack(const float* __restrict__ W,
                                              unsigned short* __restrict__ Wp) {
  int idx = blockIdx.x * 256 + threadIdx.x;   // 2048 frags
  if (idx >= 2048) return;
  int l = idx & 63, ct = idx >> 6, t = ct & 3, c = ct >> 2;
  int q = l >> 4, m = l & 15;
  #pragma unroll
  for (int j = 0; j < 8; ++j)
    Wp[idx * 8 + j] = bfbits(W[(t * 32 + q * 8 + j) * F + c * 16 + m]);
}

// ================= MFMA GEMM: H[N,128] = A[N,128] @ W =================
// 32 rows per wave (2 MFMA row-tiles share each W fragment). F32A: convert
// fp32 input in-register (layer 1). t-loop kept rolled: 8 live W frags max.
template<int F32A>
__device__ __forceinline__ bf16x8 load_frag(const void* A, int row, int off) {
  if (F32A) {
    const float* a = (const float*)A + (size_t)row * F + off;
    float4 u = *(const float4*)a, v = *(const float4*)(a + 4);
    bf16x8 r;
    r[0] = (__bf16)u.x; r[1] = (__bf16)u.y; r[2] = (__bf16)u.z; r[3] = (__bf16)u.w;
    r[4] = (__bf16)v.x; r[5] = (__bf16)v.y; r[6] = (__bf16)v.z; r[7] = (__bf16)v.w;
    return r;
  } else {
    return *(const bf16x8*)((const __bf16*)A + (size_t)row * F + off);
  }
}

template<int F32A>
__global__ __launch_bounds__(256) void k_gemm(const void* __restrict__ A,
                                              const __bf16* __restrict__ Wp,
                                              unsigned short* __restrict__ H,
                                              int nTiles, int N) {
  int gid = blockIdx.x * 4 + (threadIdx.x >> 6);
  if (gid >= nTiles) return;
  int lane = threadIdx.x & 63, m = lane & 15, q = lane >> 4;
  const int row0 = gid * 32;
  const bool has2 = (row0 + 16) < N;     // N%16==0 -> wave-uniform
  f32x4 acc[2][8];
  #pragma unroll
  for (int h = 0; h < 2; ++h)
    #pragma unroll
    for (int c = 0; c < 8; ++c) acc[h][c] = (f32x4){0.f, 0.f, 0.f, 0.f};

  const int r0 = row0 + m, r1 = row0 + 16 + m;
  #pragma unroll 1
  for (int t = 0; t < 4; ++t) {
    bf16x8 a0 = load_frag<F32A>(A, r0, q * 8 + t * 32);
    bf16x8 a1 = has2 ? load_frag<F32A>(A, r1, q * 8 + t * 32) : a0;
    #pragma unroll
    for (int c = 0; c < 8; ++c) {
      bf16x8 w = *(const bf16x8*)(Wp + ((size_t)(c * 4 + t) * 64 + lane) * 8);
      acc[0][c] = __builtin_amdgcn_mfma_f32_16x16x32_bf16(a0, w, acc[0][c], 0, 0, 0);
      acc[1][c] = __builtin_amdgcn_mfma_f32_16x16x32_bf16(a1, w, acc[1][c], 0, 0, 0);
    }
  }
  #pragma unroll
  for (int c = 0; c < 8; ++c)
    #pragma unroll
    for (int r = 0; r < 4; ++r)
      H[(size_t)(row0 + q * 4 + r) * F + c * 16 + m] = bfbits(acc[0][c][r]);
  if (has2) {
    #pragma unroll
    for (int c = 0; c < 8; ++c)
      #pragma unroll
      for (int r = 0; r < 4; ++r)
        H[(size_t)(row0 + 16 + q * 4 + r) * F + c * 16 + m] = bfbits(acc[1][c][r]);
  }
}

// ===== fused gather-aggregate + bias + LayerNorm + ReLU; 4-deep gather chains =====
__global__ __launch_bounds__(256) void k_agg_ln(const unsigned* __restrict__ Hb,
                                                const int* __restrict__ rp,
                                                const int2* __restrict__ csr,
                                                const float* __restrict__ dis,
                                                const float* __restrict__ bias,
                                                const float* __restrict__ gamma,
                                                const float* __restrict__ beta,
                                                unsigned* __restrict__ Bb, int N) {
  int n = blockIdx.x * 4 + (threadIdx.x >> 6);
  int lane = threadIdx.x & 63;
  if (n >= N) return;
  float dn = dis[n];
  int e = n ? rp[n - 1] : 0;
  int end = rp[n];
  float a0 = 0.f, a1 = 0.f, b0 = 0.f, b1 = 0.f;
  float c0 = 0.f, c1 = 0.f, d0 = 0.f, d1 = 0.f;
  for (; e + 4 <= end; e += 4) {
    int2 p0 = csr[e], p1 = csr[e + 1], p2 = csr[e + 2], p3 = csr[e + 3];
    unsigned u0 = Hb[(size_t)p0.x * 64 + lane];
    unsigned u1 = Hb[(size_t)p1.x * 64 + lane];
    unsigned u2 = Hb[(size_t)p2.x * 64 + lane];
    unsigned u3 = Hb[(size_t)p3.x * 64 + lane];
    float w0 = __int_as_float(p0.y), w1 = __int_as_float(p1.y);
    float w2 = __int_as_float(p2.y), w3 = __int_as_float(p3.y);
    a0 = fmaf(bflo(u0), w0, a0); a1 = fmaf(bfhi(u0), w0, a1);
    b0 = fmaf(bflo(u1), w1, b0); b1 = fmaf(bfhi(u1), w1, b1);
    c0 = fmaf(bflo(u2), w2, c0); c1 = fmaf(bfhi(u2), w2, c1);
    d0 = fmaf(bflo(u3), w3, d0); d1 = fmaf(bfhi(u3), w3, d1);
  }
  for (; e < end; ++e) {
    int2 p0 = csr[e];
    unsigned u0 = Hb[(size_t)p0.x * 64 + lane];
    float w0 = __int_as_float(p0.y);
    a0 = fmaf(bflo(u0), w0, a0); a1 = fmaf(bfhi(u0), w0, a1);
  }
  float e0 = (a0 + b0) + (c0 + d0);
  float e1 = (a1 + b1) + (c1 + d1);

  unsigned su = Hb[(size_t)n * 64 + lane];
  float2 bi = ((const float2*)bias)[lane];
  float v0 = e0 * dn + bflo(su) * dn * dn + bi.x;
  float v1 = e1 * dn + bfhi(su) * dn * dn + bi.y;

  float s = v0 + v1;
  #pragma unroll
  for (int o = 1; o < 64; o <<= 1) s += __shfl_xor(s, o);
  float mu = s * (1.0f / F);
  float q0 = v0 - mu, q1 = v1 - mu;
  float sq = q0 * q0 + q1 * q1;
  #pragma unroll
  for (int o = 1; o < 64; o <<= 1) sq += __shfl_xor(sq, o);
  float inv = rsqrtf(sq * (1.0f / F) + 1e-5f);
  float2 ga = ((const float2*)gamma)[lane];
  float2 be = ((const float2*)beta)[lane];
  float o0 = q0 * inv * ga.x + be.x;
  float o1 = q1 * inv * ga.y + be.y;
  Bb[(size_t)n * 64 + lane] = packbf(fmaxf(o0, 0.f), fmaxf(o1, 0.f));
}

// ================= layer 3 =================
__global__ __launch_bounds__(256) void k_layer3(const unsigned* __restrict__ Bb,
                                                const float* __restrict__ W3,
                                                float* __restrict__ h3, int N) {
  int n = blockIdx.x * 4 + (threadIdx.x >> 6);
  int lane = threadIdx.x & 63;
  if (n >= N) return;
  unsigned u = Bb[(size_t)n * 64 + lane];
  float2 w = ((const float2*)W3)[lane];
  float s = bflo(u) * w.x + bfhi(u) * w.y;
  #pragma unroll
  for (int o = 1; o < 64; o <<= 1) s += __shfl_xor(s, o);
  if (lane == 0) h3[n] = s;
}

__global__ __launch_bounds__(256) void k_out(const float* __restrict__ h3,
                                             const int* __restrict__ rp,
                                             const int2* __restrict__ csr,
                                             const float* __restrict__ dis,
                                             const float* __restrict__ b3,
                                             float* __restrict__ out, int N) {
  int n = blockIdx.x * 4 + (threadIdx.x >> 6);
  int lane = threadIdx.x & 63;
  if (n >= N) return;
  float dn = dis[n];
  int beg = n ? rp[n - 1] : 0;
  int end = rp[n];
  float s = 0.0f;
  for (int e = beg + lane; e < end; e += 64) {
    int2 c = csr[e];
    s += h3[c.x] * __int_as_float(c.y);
  }
  #pragma unroll
  for (int o = 1; o < 64; o <<= 1) s += __shfl_xor(s, o);
  if (lane == 0) out[n] = s * dn + h3[n] * dn * dn + b3[0];
}

// ================= launch =================
extern "C" void kernel_launch(void* const* d_in, const int* in_sizes, int n_in,
                              void* d_out, int out_size, void* d_ws, size_t ws_size,
                              hipStream_t stream) {
  const float* x     = (const float*)d_in[0];
  const int*   ei    = (const int*)d_in[1];
  const float* W1    = (const float*)d_in[2];
  const float* b1    = (const float*)d_in[3];
  const float* W2    = (const float*)d_in[4];
  const float* b2    = (const float*)d_in[5];
  const float* W3    = (const float*)d_in[6];
  const float* b3    = (const float*)d_in[7];
  const float* gamma = (const float*)d_in[8];
  const float* beta  = (const float*)d_in[9];
  float* out = (float*)d_out;

  const int N = in_sizes[0] / F;   // 50000
  const int E = in_sizes[1] / 2;   // 600000
  const int* src = ei;
  const int* dst = ei + E;

  // ws layout
  unsigned*       Hb      = (unsigned*)d_ws;            // N*64 (bf16 rows)
  unsigned*       Bbuf    = Hb + (size_t)N * 64;        // N*64
  unsigned short* Wp1     = (unsigned short*)(Bbuf + (size_t)N * 64); // 16384
  unsigned short* Wp2     = Wp1 + 16384;                // 16384
  int2*           csr     = (int2*)(Wp2 + 16384);       // E
  float*          dis     = (float*)(csr + E);          // N
  float*          h3      = dis + N;                    // N
  int*            deg     = (int*)(h3 + N);             // N
  int*            row_ptr = deg + N;                    // N+1
  int*            sums    = row_ptr + N + 1;            // <=256

  const int eb = (E + 255) / 256;
  const int nb = (N + 255) / 256;           // 196 (<=256 for scan2)
  const int node_blocks = (N + 3) / 4;
  const int nTiles = (N + 31) / 32;         // 1563
  const int gemm_blocks = (nTiles + 3) / 4;

  // ---- CSR build + dis ----
  hipMemsetAsync(deg, 0, (size_t)N * sizeof(int), stream);
  k_count<<<eb, 256, 0, stream>>>(dst, deg, E);
  k_scan1<<<nb, 256, 0, stream>>>(deg, row_ptr, sums, dis, N);
  k_scan2<<<1, 256, 0, stream>>>(sums, nb);
  k_scan3<<<nb, 256, 0, stream>>>(row_ptr, sums, N);
  k_fill<<<eb, 256, 0, stream>>>(src, dst, dis, row_ptr, csr, E);

  // ---- weight packs ----
  k_pack<<<8, 256, 0, stream>>>(W1, Wp1);
  k_pack<<<8, 256, 0, stream>>>(W2, Wp2);

  // ---- layer 1 (f32 input, converts in-register) ----
  k_gemm<1><<<gemm_blocks, 256, 0, stream>>>(x, (const __bf16*)Wp1,
                                             (unsigned short*)Hb, nTiles, N);
  k_agg_ln<<<node_blocks, 256, 0, stream>>>(Hb, row_ptr, csr, dis, b1, gamma, beta, Bbuf, N);

  // ---- layer 2 ----
  k_gemm<0><<<gemm_blocks, 256, 0, stream>>>(Bbuf, (const __bf16*)Wp2,
                                             (unsigned short*)Hb, nTiles, N);
  k_agg_ln<<<node_blocks, 256, 0, stream>>>(Hb, row_ptr, csr, dis, b2, gamma, beta, Bbuf, N);

  // ---- layer 3 ----
  k_layer3<<<node_blocks, 256, 0, stream>>>(Bbuf, W3, h3, N);
  k_out<<<node_blocks, 256, 0, stream>>>(h3, row_ptr, csr, dis, b3, out, N);
}

// Round 6
// 242.242 us; speedup vs baseline: 14.6241x; 1.1102x over previous
//
#include <hip/hip_runtime.h>

#define F 128

typedef __attribute__((ext_vector_type(8))) __bf16 bf16x8;
typedef __attribute__((ext_vector_type(4))) float f32x4;

__device__ __forceinline__ float bflo(unsigned u) { return __uint_as_float(u << 16); }
__device__ __forceinline__ float bfhi(unsigned u) { return __uint_as_float(u & 0xffff0000u); }
__device__ __forceinline__ unsigned short bfbits(float f) {
  __bf16 h = (__bf16)f;
  union { __bf16 b; unsigned short s; } v; v.b = h; return v.s;
}
__device__ __forceinline__ unsigned packbf(float a, float b) {
  return (unsigned)bfbits(a) | ((unsigned)bfbits(b) << 16);
}

// ================= CSR build =================
// 4 edges per thread via int4
__global__ __launch_bounds__(256) void k_count(const int* __restrict__ dst,
                                               int* __restrict__ deg, int E) {
  int base = (blockIdx.x * 256 + threadIdx.x) * 4;
  if (base + 3 < E) {
    int4 d = *(const int4*)(dst + base);
    atomicAdd(&deg[d.x], 1); atomicAdd(&deg[d.y], 1);
    atomicAdd(&deg[d.z], 1); atomicAdd(&deg[d.w], 1);
  } else {
    for (int k = base; k < E; ++k) atomicAdd(&deg[dst[k]], 1);
  }
}

// scan pass 1 + dis = rsqrt(deg+1) fused
__global__ __launch_bounds__(256) void k_scan1(const int* __restrict__ deg,
                                               int* __restrict__ row_ptr,
                                               int* __restrict__ sums,
                                               float* __restrict__ dis, int N) {
  int i = blockIdx.x * 256 + threadIdx.x;
  int lane = threadIdx.x & 63, wid = threadIdx.x >> 6;
  int d = (i < N) ? deg[i] : 0;
  if (i < N) dis[i] = rsqrtf((float)d + 1.0f);
  int v = d;
  #pragma unroll
  for (int o = 1; o < 64; o <<= 1) {
    int t = __shfl_up(v, o);
    if (lane >= o) v += t;
  }
  __shared__ int wsum[4];
  if (lane == 63) wsum[wid] = v;
  __syncthreads();
  if (threadIdx.x == 0) {
    int run = 0;
    #pragma unroll
    for (int w = 0; w < 4; ++w) { run += wsum[w]; wsum[w] = run; }
    sums[blockIdx.x] = run;
  }
  __syncthreads();
  if (wid > 0) v += wsum[wid - 1];
  if (i < N) row_ptr[i + 1] = v;
}

__global__ __launch_bounds__(256) void k_scan2(int* __restrict__ sums, int nb) {
  int t = threadIdx.x;
  int lane = t & 63, wid = t >> 6;
  int orig = (t < nb) ? sums[t] : 0;
  int v = orig;
  #pragma unroll
  for (int o = 1; o < 64; o <<= 1) {
    int u = __shfl_up(v, o);
    if (lane >= o) v += u;
  }
  __shared__ int wsum[4];
  if (lane == 63) wsum[wid] = v;
  __syncthreads();
  if (t == 0) {
    int run = 0;
    #pragma unroll
    for (int w = 0; w < 4; ++w) { run += wsum[w]; wsum[w] = run; }
  }
  __syncthreads();
  if (wid > 0) v += wsum[wid - 1];
  if (t < nb) sums[t] = v - orig;
}

__global__ __launch_bounds__(256) void k_scan3(int* __restrict__ row_ptr,
                                               const int* __restrict__ sums, int N) {
  int i = blockIdx.x * 256 + threadIdx.x;
  if (i == 0) row_ptr[0] = 0;
  if (i < N) row_ptr[i + 1] += sums[blockIdx.x];
}

// k_fill bumps row_ptr[dst] directly. POST-FILL: seg(n) = [ n? rp[n-1]:0 , rp[n] )
__global__ __launch_bounds__(256) void k_fill(const int* __restrict__ src,
                                              const int* __restrict__ dst,
                                              const float* __restrict__ dis,
                                              int* __restrict__ row_ptr,
                                              int2* __restrict__ csr, int E) {
  int base = (blockIdx.x * 256 + threadIdx.x) * 4;
  if (base + 3 < E) {
    int4 s = *(const int4*)(src + base);
    int4 d = *(const int4*)(dst + base);
    int p0 = atomicAdd(&row_ptr[d.x], 1);
    int p1 = atomicAdd(&row_ptr[d.y], 1);
    int p2 = atomicAdd(&row_ptr[d.z], 1);
    int p3 = atomicAdd(&row_ptr[d.w], 1);
    csr[p0] = make_int2(s.x, __float_as_int(dis[s.x]));
    csr[p1] = make_int2(s.y, __float_as_int(dis[s.y]));
    csr[p2] = make_int2(s.z, __float_as_int(dis[s.z]));
    csr[p3] = make_int2(s.w, __float_as_int(dis[s.w]));
  } else {
    for (int k = base; k < E; ++k) {
      int s = src[k];
      int pos = atomicAdd(&row_ptr[dst[k]], 1);
      csr[pos] = make_int2(s, __float_as_int(dis[s]));
    }
  }
}

// ================= pack W[128,128] into B-fragment order =================
__global__ __launch_bounds__(256) void k_pack(const float* __restrict__ W,
                                              unsigned short* __restrict__ Wp) {
  int idx = blockIdx.x * 256 + threadIdx.x;   // 2048 frags
  if (idx >= 2048) return;
  int l = idx & 63, ct = idx >> 6, t = ct & 3, c = ct >> 2;
  int q = l >> 4, m = l & 15;
  #pragma unroll
  for (int j = 0; j < 8; ++j)
    Wp[idx * 8 + j] = bfbits(W[(t * 32 + q * 8 + j) * F + c * 16 + m]);
}

// ================= MFMA GEMM: H[N,128] = A[N,128] @ W =================
template<int F32A>
__device__ __forceinline__ bf16x8 load_frag(const void* A, int row, int off) {
  if (F32A) {
    const float* a = (const float*)A + (size_t)row * F + off;
    float4 u = *(const float4*)a, v = *(const float4*)(a + 4);
    bf16x8 r;
    r[0] = (__bf16)u.x; r[1] = (__bf16)u.y; r[2] = (__bf16)u.z; r[3] = (__bf16)u.w;
    r[4] = (__bf16)v.x; r[5] = (__bf16)v.y; r[6] = (__bf16)v.z; r[7] = (__bf16)v.w;
    return r;
  } else {
    return *(const bf16x8*)((const __bf16*)A + (size_t)row * F + off);
  }
}

template<int F32A>
__global__ __launch_bounds__(256) void k_gemm(const void* __restrict__ A,
                                              const __bf16* __restrict__ Wp,
                                              unsigned short* __restrict__ H,
                                              int nTiles, int N) {
  int gid = blockIdx.x * 4 + (threadIdx.x >> 6);
  if (gid >= nTiles) return;
  int lane = threadIdx.x & 63, m = lane & 15, q = lane >> 4;
  const int row0 = gid * 32;
  const bool has2 = (row0 + 16) < N;
  f32x4 acc[2][8];
  #pragma unroll
  for (int h = 0; h < 2; ++h)
    #pragma unroll
    for (int c = 0; c < 8; ++c) acc[h][c] = (f32x4){0.f, 0.f, 0.f, 0.f};

  const int r0 = row0 + m, r1 = row0 + 16 + m;
  #pragma unroll 1
  for (int t = 0; t < 4; ++t) {
    bf16x8 a0 = load_frag<F32A>(A, r0, q * 8 + t * 32);
    bf16x8 a1 = has2 ? load_frag<F32A>(A, r1, q * 8 + t * 32) : a0;
    #pragma unroll
    for (int c = 0; c < 8; ++c) {
      bf16x8 w = *(const bf16x8*)(Wp + ((size_t)(c * 4 + t) * 64 + lane) * 8);
      acc[0][c] = __builtin_amdgcn_mfma_f32_16x16x32_bf16(a0, w, acc[0][c], 0, 0, 0);
      acc[1][c] = __builtin_amdgcn_mfma_f32_16x16x32_bf16(a1, w, acc[1][c], 0, 0, 0);
    }
  }
  #pragma unroll
  for (int c = 0; c < 8; ++c)
    #pragma unroll
    for (int r = 0; r < 4; ++r)
      H[(size_t)(row0 + q * 4 + r) * F + c * 16 + m] = bfbits(acc[0][c][r]);
  if (has2) {
    #pragma unroll
    for (int c = 0; c < 8; ++c)
      #pragma unroll
      for (int r = 0; r < 4; ++r)
        H[(size_t)(row0 + 16 + q * 4 + r) * F + c * 16 + m] = bfbits(acc[1][c][r]);
  }
}

// ===== gather-agg + bias + LN + ReLU (+ optional fused W3 dot) =====
// 16-lane group per node (4 nodes/wave, 16/block). Lane covers 8 features via
// one uint4 (16B) gather per edge -> 4x fewer VMEM instrs than dword/lane.
template<int FUSE3>
__global__ __launch_bounds__(256) void k_agg_ln(const unsigned* __restrict__ Hb,
                                                const int* __restrict__ rp,
                                                const int2* __restrict__ csr,
                                                const float* __restrict__ dis,
                                                const float* __restrict__ bias,
                                                const float* __restrict__ gamma,
                                                const float* __restrict__ beta,
                                                const float* __restrict__ W3,
                                                float* __restrict__ h3,
                                                unsigned* __restrict__ Bb, int N) {
  int tid = threadIdx.x;
  int l = tid & 15;                       // lane in group
  int n = blockIdx.x * 16 + (tid >> 4);   // node
  if (n >= N) return;
  float dn = dis[n];
  int e = n ? rp[n - 1] : 0;
  int end = rp[n];

  float a[8] = {}, b[8] = {};
  for (; e + 2 <= end; e += 2) {
    int2 p0 = csr[e], p1 = csr[e + 1];
    uint4 r0 = *(const uint4*)(Hb + (size_t)p0.x * 64 + l * 4);
    uint4 r1 = *(const uint4*)(Hb + (size_t)p1.x * 64 + l * 4);
    float w0 = __int_as_float(p0.y), w1 = __int_as_float(p1.y);
    a[0] = fmaf(bflo(r0.x), w0, a[0]); a[1] = fmaf(bfhi(r0.x), w0, a[1]);
    a[2] = fmaf(bflo(r0.y), w0, a[2]); a[3] = fmaf(bfhi(r0.y), w0, a[3]);
    a[4] = fmaf(bflo(r0.z), w0, a[4]); a[5] = fmaf(bfhi(r0.z), w0, a[5]);
    a[6] = fmaf(bflo(r0.w), w0, a[6]); a[7] = fmaf(bfhi(r0.w), w0, a[7]);
    b[0] = fmaf(bflo(r1.x), w1, b[0]); b[1] = fmaf(bfhi(r1.x), w1, b[1]);
    b[2] = fmaf(bflo(r1.y), w1, b[2]); b[3] = fmaf(bfhi(r1.y), w1, b[3]);
    b[4] = fmaf(bflo(r1.z), w1, b[4]); b[5] = fmaf(bfhi(r1.z), w1, b[5]);
    b[6] = fmaf(bflo(r1.w), w1, b[6]); b[7] = fmaf(bfhi(r1.w), w1, b[7]);
  }
  if (e < end) {
    int2 p0 = csr[e];
    uint4 r0 = *(const uint4*)(Hb + (size_t)p0.x * 64 + l * 4);
    float w0 = __int_as_float(p0.y);
    a[0] = fmaf(bflo(r0.x), w0, a[0]); a[1] = fmaf(bfhi(r0.x), w0, a[1]);
    a[2] = fmaf(bflo(r0.y), w0, a[2]); a[3] = fmaf(bfhi(r0.y), w0, a[3]);
    a[4] = fmaf(bflo(r0.z), w0, a[4]); a[5] = fmaf(bfhi(r0.z), w0, a[5]);
    a[6] = fmaf(bflo(r0.w), w0, a[6]); a[7] = fmaf(bfhi(r0.w), w0, a[7]);
  }

  uint4 su = *(const uint4*)(Hb + (size_t)n * 64 + l * 4);
  float self[8] = { bflo(su.x), bfhi(su.x), bflo(su.y), bfhi(su.y),
                    bflo(su.z), bfhi(su.z), bflo(su.w), bfhi(su.w) };
  float4 bi0 = ((const float4*)bias)[l * 2], bi1 = ((const float4*)bias)[l * 2 + 1];
  float bi[8] = { bi0.x, bi0.y, bi0.z, bi0.w, bi1.x, bi1.y, bi1.z, bi1.w };
  float dn2 = dn * dn;
  float v[8];
  float s = 0.f;
  #pragma unroll
  for (int k = 0; k < 8; ++k) {
    v[k] = (a[k] + b[k]) * dn + self[k] * dn2 + bi[k];
    s += v[k];
  }
  #pragma unroll
  for (int o = 1; o < 16; o <<= 1) s += __shfl_xor(s, o);
  float mu = s * (1.0f / F);
  float sq = 0.f;
  #pragma unroll
  for (int k = 0; k < 8; ++k) { v[k] -= mu; sq += v[k] * v[k]; }
  #pragma unroll
  for (int o = 1; o < 16; o <<= 1) sq += __shfl_xor(sq, o);
  float inv = rsqrtf(sq * (1.0f / F) + 1e-5f);

  float4 ga0 = ((const float4*)gamma)[l * 2], ga1 = ((const float4*)gamma)[l * 2 + 1];
  float4 be0 = ((const float4*)beta)[l * 2],  be1 = ((const float4*)beta)[l * 2 + 1];
  float ga[8] = { ga0.x, ga0.y, ga0.z, ga0.w, ga1.x, ga1.y, ga1.z, ga1.w };
  float be[8] = { be0.x, be0.y, be0.z, be0.w, be1.x, be1.y, be1.z, be1.w };
  float o8[8];
  #pragma unroll
  for (int k = 0; k < 8; ++k) o8[k] = fmaxf(v[k] * inv * ga[k] + be[k], 0.f);

  uint4 outv;
  outv.x = packbf(o8[0], o8[1]); outv.y = packbf(o8[2], o8[3]);
  outv.z = packbf(o8[4], o8[5]); outv.w = packbf(o8[6], o8[7]);
  *(uint4*)(Bb + (size_t)n * 64 + l * 4) = outv;

  if (FUSE3) {
    // h3[n] = dot(relu_out_row, W3) on the bf16-rounded values (match unfused path)
    float4 w30 = ((const float4*)W3)[l * 2], w31 = ((const float4*)W3)[l * 2 + 1];
    float w3[8] = { w30.x, w30.y, w30.z, w30.w, w31.x, w31.y, w31.z, w31.w };
    float s3 = 0.f;
    #pragma unroll
    for (int k = 0; k < 8; ++k) {
      float q = (k & 1) ? bfhi(((unsigned*)&outv)[k >> 1]) : bflo(((unsigned*)&outv)[k >> 1]);
      s3 += q * w3[k];
    }
    #pragma unroll
    for (int o = 1; o < 16; o <<= 1) s3 += __shfl_xor(s3, o);
    if (l == 0) h3[n] = s3;
  }
}

// ================= output gather: 8-lane group per node =================
__global__ __launch_bounds__(256) void k_out(const float* __restrict__ h3,
                                             const int* __restrict__ rp,
                                             const int2* __restrict__ csr,
                                             const float* __restrict__ dis,
                                             const float* __restrict__ b3,
                                             float* __restrict__ out, int N) {
  int tid = threadIdx.x;
  int l = tid & 7;
  int n = blockIdx.x * 32 + (tid >> 3);
  if (n >= N) return;
  float dn = dis[n];
  int beg = n ? rp[n - 1] : 0;
  int end = rp[n];
  float s = 0.0f;
  for (int e = beg + l; e < end; e += 8) {
    int2 c = csr[e];
    s += h3[c.x] * __int_as_float(c.y);
  }
  #pragma unroll
  for (int o = 1; o < 8; o <<= 1) s += __shfl_xor(s, o);
  if (l == 0) out[n] = s * dn + h3[n] * dn * dn + b3[0];
}

// ================= launch =================
extern "C" void kernel_launch(void* const* d_in, const int* in_sizes, int n_in,
                              void* d_out, int out_size, void* d_ws, size_t ws_size,
                              hipStream_t stream) {
  const float* x     = (const float*)d_in[0];
  const int*   ei    = (const int*)d_in[1];
  const float* W1    = (const float*)d_in[2];
  const float* b1    = (const float*)d_in[3];
  const float* W2    = (const float*)d_in[4];
  const float* b2    = (const float*)d_in[5];
  const float* W3    = (const float*)d_in[6];
  const float* b3    = (const float*)d_in[7];
  const float* gamma = (const float*)d_in[8];
  const float* beta  = (const float*)d_in[9];
  float* out = (float*)d_out;

  const int N = in_sizes[0] / F;   // 50000
  const int E = in_sizes[1] / 2;   // 600000
  const int* src = ei;
  const int* dst = ei + E;

  unsigned*       Hb      = (unsigned*)d_ws;            // N*64 (bf16 rows)
  unsigned*       Bbuf    = Hb + (size_t)N * 64;        // N*64
  unsigned short* Wp1     = (unsigned short*)(Bbuf + (size_t)N * 64); // 16384
  unsigned short* Wp2     = Wp1 + 16384;                // 16384
  int2*           csr     = (int2*)(Wp2 + 16384);       // E
  float*          dis     = (float*)(csr + E);          // N
  float*          h3      = dis + N;                    // N
  int*            deg     = (int*)(h3 + N);             // N
  int*            row_ptr = deg + N;                    // N+1
  int*            sums    = row_ptr + N + 1;            // <=256

  const int e4b = (E / 4 + 255) / 256;
  const int nb = (N + 255) / 256;           // 196 (<=256 for scan2)
  const int agg_blocks = (N + 15) / 16;     // 3125
  const int out_blocks = (N + 31) / 32;
  const int nTiles = (N + 31) / 32;
  const int gemm_blocks = (nTiles + 3) / 4;

  // ---- CSR build + dis ----
  hipMemsetAsync(deg, 0, (size_t)N * sizeof(int), stream);
  k_count<<<e4b, 256, 0, stream>>>(dst, deg, E);
  k_scan1<<<nb, 256, 0, stream>>>(deg, row_ptr, sums, dis, N);
  k_scan2<<<1, 256, 0, stream>>>(sums, nb);
  k_scan3<<<nb, 256, 0, stream>>>(row_ptr, sums, N);
  k_fill<<<e4b, 256, 0, stream>>>(src, dst, dis, row_ptr, csr, E);

  // ---- weight packs ----
  k_pack<<<8, 256, 0, stream>>>(W1, Wp1);
  k_pack<<<8, 256, 0, stream>>>(W2, Wp2);

  // ---- layer 1 ----
  k_gemm<1><<<gemm_blocks, 256, 0, stream>>>(x, (const __bf16*)Wp1,
                                             (unsigned short*)Hb, nTiles, N);
  k_agg_ln<0><<<agg_blocks, 256, 0, stream>>>(Hb, row_ptr, csr, dis, b1, gamma, beta,
                                              nullptr, nullptr, Bbuf, N);

  // ---- layer 2 (+ fused W3 dot -> h3) ----
  k_gemm<0><<<gemm_blocks, 256, 0, stream>>>(Bbuf, (const __bf16*)Wp2,
                                             (unsigned short*)Hb, nTiles, N);
  k_agg_ln<1><<<agg_blocks, 256, 0, stream>>>(Hb, row_ptr, csr, dis, b2, gamma, beta,
                                              W3, h3, Bbuf, N);

  // ---- layer 3 aggregation ----
  k_out<<<out_blocks, 256, 0, stream>>>(h3, row_ptr, csr, dis, b3, out, N);
}

// Round 7
// 238.942 us; speedup vs baseline: 14.8261x; 1.0138x over previous
//
#include <hip/hip_runtime.h>

#define F 128

typedef __attribute__((ext_vector_type(8))) __bf16 bf16x8;
typedef __attribute__((ext_vector_type(4))) float f32x4;

__device__ __forceinline__ float bflo(unsigned u) { return __uint_as_float(u << 16); }
__device__ __forceinline__ float bfhi(unsigned u) { return __uint_as_float(u & 0xffff0000u); }
__device__ __forceinline__ unsigned short bfbits(float f) {
  __bf16 h = (__bf16)f;
  union { __bf16 b; unsigned short s; } v; v.b = h; return v.s;
}
__device__ __forceinline__ unsigned packbf(float a, float b) {
  return (unsigned)bfbits(a) | ((unsigned)bfbits(b) << 16);
}

// ========== K_A: edge count histogram  ∪  W1 pack  ∪  W2 pack ==========
__device__ __forceinline__ void pack_body(const float* __restrict__ W,
                                          unsigned short* __restrict__ Wp, int idx) {
  int l = idx & 63, ct = idx >> 6, t = ct & 3, c = ct >> 2;
  int q = l >> 4, m = l & 15;
  #pragma unroll
  for (int j = 0; j < 8; ++j)
    Wp[idx * 8 + j] = bfbits(W[(t * 32 + q * 8 + j) * F + c * 16 + m]);
}

__global__ __launch_bounds__(256) void k_count_pack(const int* __restrict__ dst,
                                                    int* __restrict__ deg, int E, int cb,
                                                    const float* __restrict__ W1,
                                                    unsigned short* __restrict__ Wp1,
                                                    const float* __restrict__ W2,
                                                    unsigned short* __restrict__ Wp2) {
  int b = blockIdx.x;
  if (b < cb) {
    int base = (b * 256 + threadIdx.x) * 4;
    if (base + 3 < E) {
      int4 d = *(const int4*)(dst + base);
      atomicAdd(&deg[d.x], 1); atomicAdd(&deg[d.y], 1);
      atomicAdd(&deg[d.z], 1); atomicAdd(&deg[d.w], 1);
    } else {
      for (int k = base; k < E; ++k) atomicAdd(&deg[dst[k]], 1);
    }
  } else if (b < cb + 8) {
    pack_body(W1, Wp1, (b - cb) * 256 + threadIdx.x);
  } else {
    pack_body(W2, Wp2, (b - cb - 8) * 256 + threadIdx.x);
  }
}

// ========== single-kernel decoupled-lookback scan (+ dis = rsqrt(deg+1)) ==========
// status[b] packed: flag(<<32) | blocksum.  1 = aggregate ready, 2 = prefix ready.
__global__ __launch_bounds__(256) void k_scan(const int* __restrict__ deg,
                                              int* __restrict__ row_ptr,
                                              float* __restrict__ dis,
                                              unsigned long long* __restrict__ status,
                                              int* __restrict__ dyn_ctr, int N) {
  __shared__ int s_bid;
  if (threadIdx.x == 0) s_bid = atomicAdd(dyn_ctr, 1);
  __syncthreads();
  const int bid = s_bid;
  int i = bid * 256 + threadIdx.x;
  int lane = threadIdx.x & 63, wid = threadIdx.x >> 6;
  int d = (i < N) ? deg[i] : 0;
  if (i < N) dis[i] = rsqrtf((float)d + 1.0f);
  int v = d;
  #pragma unroll
  for (int o = 1; o < 64; o <<= 1) {
    int t = __shfl_up(v, o);
    if (lane >= o) v += t;
  }
  __shared__ int wsum[4];
  __shared__ int s_excl;
  if (lane == 63) wsum[wid] = v;
  __syncthreads();
  if (threadIdx.x == 0) {
    int run = 0;
    #pragma unroll
    for (int w = 0; w < 4; ++w) { run += wsum[w]; wsum[w] = run; }
    int total = run;
    // publish aggregate (or prefix if block 0)
    unsigned long long st = ((unsigned long long)(bid == 0 ? 2 : 1) << 32) |
                            (unsigned long long)(unsigned)total;
    atomicExch(&status[bid], st);
    int excl = 0;
    if (bid > 0) {
      int j = bid - 1;
      while (true) {
        unsigned long long s = atomicAdd(&status[j], 0ULL);
        unsigned flag = (unsigned)(s >> 32);
        if (flag == 0) { __builtin_amdgcn_s_sleep(1); continue; }
        excl += (int)(unsigned)s;
        if (flag == 2) break;
        --j;
      }
      atomicExch(&status[bid], (2ULL << 32) | (unsigned long long)(unsigned)(excl + total));
    }
    s_excl = excl;
  }
  __syncthreads();
  int excl = s_excl;
  if (wid > 0) v += wsum[wid - 1];
  if (i < N) row_ptr[i + 1] = excl + v;
  if (i == 0) row_ptr[0] = 0;
}

// ========== K_B: CSR fill (src only)  ∪  layer-1 GEMM ==========
// fill: pos = atomicAdd(row_ptr[dst]); csr_src[pos] = src.
// POST-FILL: seg(n) = [ n? rp[n-1]:0 , rp[n] )
template<int F32A>
__device__ __forceinline__ bf16x8 load_frag(const void* A, int row, int off) {
  if (F32A) {
    const float* a = (const float*)A + (size_t)row * F + off;
    float4 u = *(const float4*)a, v = *(const float4*)(a + 4);
    bf16x8 r;
    r[0] = (__bf16)u.x; r[1] = (__bf16)u.y; r[2] = (__bf16)u.z; r[3] = (__bf16)u.w;
    r[4] = (__bf16)v.x; r[5] = (__bf16)v.y; r[6] = (__bf16)v.z; r[7] = (__bf16)v.w;
    return r;
  } else {
    return *(const bf16x8*)((const __bf16*)A + (size_t)row * F + off);
  }
}

// GEMM body: H'[row] = bf16( (A[row]@W) * dis[row] )  — dis folded into rows
template<int F32A>
__device__ __forceinline__ void gemm_body(const void* __restrict__ A,
                                          const __bf16* __restrict__ Wp,
                                          const float* __restrict__ dis,
                                          unsigned short* __restrict__ H,
                                          int gid, int tid, int N) {
  int lane = tid & 63, m = lane & 15, q = lane >> 4;
  const int row0 = gid * 32;
  const bool has2 = (row0 + 16) < N;
  f32x4 acc[2][8];
  #pragma unroll
  for (int h = 0; h < 2; ++h)
    #pragma unroll
    for (int c = 0; c < 8; ++c) acc[h][c] = (f32x4){0.f, 0.f, 0.f, 0.f};

  const int r0 = row0 + m, r1 = row0 + 16 + m;
  #pragma unroll 1
  for (int t = 0; t < 4; ++t) {
    bf16x8 a0 = load_frag<F32A>(A, r0, q * 8 + t * 32);
    bf16x8 a1 = has2 ? load_frag<F32A>(A, r1, q * 8 + t * 32) : a0;
    #pragma unroll
    for (int c = 0; c < 8; ++c) {
      bf16x8 w = *(const bf16x8*)(Wp + ((size_t)(c * 4 + t) * 64 + lane) * 8);
      acc[0][c] = __builtin_amdgcn_mfma_f32_16x16x32_bf16(a0, w, acc[0][c], 0, 0, 0);
      acc[1][c] = __builtin_amdgcn_mfma_f32_16x16x32_bf16(a1, w, acc[1][c], 0, 0, 0);
    }
  }
  float dr0[4], dr1[4];
  #pragma unroll
  for (int r = 0; r < 4; ++r) {
    dr0[r] = dis[row0 + q * 4 + r];
    dr1[r] = has2 ? dis[row0 + 16 + q * 4 + r] : 1.f;
  }
  #pragma unroll
  for (int c = 0; c < 8; ++c)
    #pragma unroll
    for (int r = 0; r < 4; ++r)
      H[(size_t)(row0 + q * 4 + r) * F + c * 16 + m] = bfbits(acc[0][c][r] * dr0[r]);
  if (has2) {
    #pragma unroll
    for (int c = 0; c < 8; ++c)
      #pragma unroll
      for (int r = 0; r < 4; ++r)
        H[(size_t)(row0 + 16 + q * 4 + r) * F + c * 16 + m] = bfbits(acc[1][c][r] * dr1[r]);
  }
}

__global__ __launch_bounds__(256) void k_fill_gemm1(const int* __restrict__ src,
                                                    const int* __restrict__ dst,
                                                    int* __restrict__ row_ptr,
                                                    int* __restrict__ csr_src, int E, int fb,
                                                    const float* __restrict__ x,
                                                    const __bf16* __restrict__ Wp1,
                                                    const float* __restrict__ dis,
                                                    unsigned short* __restrict__ H,
                                                    int nTiles, int N) {
  int b = blockIdx.x;
  if (b < fb) {
    int base = (b * 256 + threadIdx.x) * 4;
    if (base + 3 < E) {
      int4 s = *(const int4*)(src + base);
      int4 d = *(const int4*)(dst + base);
      int p0 = atomicAdd(&row_ptr[d.x], 1);
      int p1 = atomicAdd(&row_ptr[d.y], 1);
      int p2 = atomicAdd(&row_ptr[d.z], 1);
      int p3 = atomicAdd(&row_ptr[d.w], 1);
      csr_src[p0] = s.x; csr_src[p1] = s.y; csr_src[p2] = s.z; csr_src[p3] = s.w;
    } else {
      for (int k = base; k < E; ++k) {
        int pos = atomicAdd(&row_ptr[dst[k]], 1);
        csr_src[pos] = src[k];
      }
    }
  } else {
    int gid = (b - fb) * 4 + (threadIdx.x >> 6);
    if (gid < nTiles) gemm_body<1>(x, Wp1, dis, H, gid, threadIdx.x, N);
  }
}

__global__ __launch_bounds__(256) void k_gemm2(const void* __restrict__ A,
                                               const __bf16* __restrict__ Wp,
                                               const float* __restrict__ dis,
                                               unsigned short* __restrict__ H,
                                               int nTiles, int N) {
  int gid = blockIdx.x * 4 + (threadIdx.x >> 6);
  if (gid < nTiles) gemm_body<0>(A, Wp, dis, H, gid, threadIdx.x, N);
}

// ===== gather-agg (pure row sum) + bias + LN + ReLU (+ fused W3 dot -> h3') =====
// 16-lane group per node; lane covers 8 features via one uint4 gather per edge.
template<int FUSE3>
__global__ __launch_bounds__(256) void k_agg_ln(const unsigned* __restrict__ Hb,
                                                const int* __restrict__ rp,
                                                const int* __restrict__ csr,
                                                const float* __restrict__ dis,
                                                const float* __restrict__ bias,
                                                const float* __restrict__ gamma,
                                                const float* __restrict__ beta,
                                                const float* __restrict__ W3,
                                                float* __restrict__ h3p,
                                                unsigned* __restrict__ Bb, int N) {
  int tid = threadIdx.x;
  int l = tid & 15;
  int n = blockIdx.x * 16 + (tid >> 4);
  if (n >= N) return;
  float dn = dis[n];
  int e = n ? rp[n - 1] : 0;
  int end = rp[n];

  float a[8] = {}, b[8] = {};
  for (; e + 2 <= end; e += 2) {
    int s0 = csr[e], s1 = csr[e + 1];
    uint4 r0 = *(const uint4*)(Hb + (size_t)s0 * 64 + l * 4);
    uint4 r1 = *(const uint4*)(Hb + (size_t)s1 * 64 + l * 4);
    a[0] += bflo(r0.x); a[1] += bfhi(r0.x); a[2] += bflo(r0.y); a[3] += bfhi(r0.y);
    a[4] += bflo(r0.z); a[5] += bfhi(r0.z); a[6] += bflo(r0.w); a[7] += bfhi(r0.w);
    b[0] += bflo(r1.x); b[1] += bfhi(r1.x); b[2] += bflo(r1.y); b[3] += bfhi(r1.y);
    b[4] += bflo(r1.z); b[5] += bfhi(r1.z); b[6] += bflo(r1.w); b[7] += bfhi(r1.w);
  }
  if (e < end) {
    int s0 = csr[e];
    uint4 r0 = *(const uint4*)(Hb + (size_t)s0 * 64 + l * 4);
    a[0] += bflo(r0.x); a[1] += bfhi(r0.x); a[2] += bflo(r0.y); a[3] += bfhi(r0.y);
    a[4] += bflo(r0.z); a[5] += bfhi(r0.z); a[6] += bflo(r0.w); a[7] += bfhi(r0.w);
  }

  uint4 su = *(const uint4*)(Hb + (size_t)n * 64 + l * 4);
  float self[8] = { bflo(su.x), bfhi(su.x), bflo(su.y), bfhi(su.y),
                    bflo(su.z), bfhi(su.z), bflo(su.w), bfhi(su.w) };
  float4 bi0 = ((const float4*)bias)[l * 2], bi1 = ((const float4*)bias)[l * 2 + 1];
  float bi[8] = { bi0.x, bi0.y, bi0.z, bi0.w, bi1.x, bi1.y, bi1.z, bi1.w };
  float v[8];
  float s = 0.f;
  #pragma unroll
  for (int k = 0; k < 8; ++k) {
    v[k] = (a[k] + b[k] + self[k]) * dn + bi[k];
    s += v[k];
  }
  #pragma unroll
  for (int o = 1; o < 16; o <<= 1) s += __shfl_xor(s, o);
  float mu = s * (1.0f / F);
  float sq = 0.f;
  #pragma unroll
  for (int k = 0; k < 8; ++k) { v[k] -= mu; sq += v[k] * v[k]; }
  #pragma unroll
  for (int o = 1; o < 16; o <<= 1) sq += __shfl_xor(sq, o);
  float inv = rsqrtf(sq * (1.0f / F) + 1e-5f);

  float4 ga0 = ((const float4*)gamma)[l * 2], ga1 = ((const float4*)gamma)[l * 2 + 1];
  float4 be0 = ((const float4*)beta)[l * 2],  be1 = ((const float4*)beta)[l * 2 + 1];
  float ga[8] = { ga0.x, ga0.y, ga0.z, ga0.w, ga1.x, ga1.y, ga1.z, ga1.w };
  float be[8] = { be0.x, be0.y, be0.z, be0.w, be1.x, be1.y, be1.z, be1.w };
  float o8[8];
  #pragma unroll
  for (int k = 0; k < 8; ++k) o8[k] = fmaxf(v[k] * inv * ga[k] + be[k], 0.f);

  uint4 outv;
  outv.x = packbf(o8[0], o8[1]); outv.y = packbf(o8[2], o8[3]);
  outv.z = packbf(o8[4], o8[5]); outv.w = packbf(o8[6], o8[7]);
  *(uint4*)(Bb + (size_t)n * 64 + l * 4) = outv;

  if (FUSE3) {
    // h3'[n] = dot(relu_row_bf16, W3) * dis[n]
    float4 w30 = ((const float4*)W3)[l * 2], w31 = ((const float4*)W3)[l * 2 + 1];
    float w3[8] = { w30.x, w30.y, w30.z, w30.w, w31.x, w31.y, w31.z, w31.w };
    float s3 = 0.f;
    #pragma unroll
    for (int k = 0; k < 8; ++k) {
      float q = (k & 1) ? bfhi(((unsigned*)&outv)[k >> 1]) : bflo(((unsigned*)&outv)[k >> 1]);
      s3 += q * w3[k];
    }
    #pragma unroll
    for (int o = 1; o < 16; o <<= 1) s3 += __shfl_xor(s3, o);
    if (l == 0) h3p[n] = s3 * dn;
  }
}

// ========== output gather: out[n] = dn*(sum h3'[src] + h3'[n]) + b3 ==========
__global__ __launch_bounds__(256) void k_out(const float* __restrict__ h3p,
                                             const int* __restrict__ rp,
                                             const int* __restrict__ csr,
                                             const float* __restrict__ dis,
                                             const float* __restrict__ b3,
                                             float* __restrict__ out, int N) {
  int tid = threadIdx.x;
  int l = tid & 7;
  int n = blockIdx.x * 32 + (tid >> 3);
  if (n >= N) return;
  float dn = dis[n];
  int beg = n ? rp[n - 1] : 0;
  int end = rp[n];
  float s = 0.0f;
  for (int e = beg + l; e < end; e += 8) s += h3p[csr[e]];
  #pragma unroll
  for (int o = 1; o < 8; o <<= 1) s += __shfl_xor(s, o);
  if (l == 0) out[n] = (s + h3p[n]) * dn + b3[0];
}

// ================= launch =================
extern "C" void kernel_launch(void* const* d_in, const int* in_sizes, int n_in,
                              void* d_out, int out_size, void* d_ws, size_t ws_size,
                              hipStream_t stream) {
  const float* x     = (const float*)d_in[0];
  const int*   ei    = (const int*)d_in[1];
  const float* W1    = (const float*)d_in[2];
  const float* b1    = (const float*)d_in[3];
  const float* W2    = (const float*)d_in[4];
  const float* b2    = (const float*)d_in[5];
  const float* W3    = (const float*)d_in[6];
  const float* b3    = (const float*)d_in[7];
  const float* gamma = (const float*)d_in[8];
  const float* beta  = (const float*)d_in[9];
  float* out = (float*)d_out;

  const int N = in_sizes[0] / F;   // 50000
  const int E = in_sizes[1] / 2;   // 600000
  const int* src = ei;
  const int* dst = ei + E;

  const int nb = (N + 255) / 256;           // 196 scan blocks

  unsigned*           Hb      = (unsigned*)d_ws;                       // N*64
  unsigned*           Bbuf    = Hb + (size_t)N * 64;                   // N*64
  unsigned short*     Wp1     = (unsigned short*)(Bbuf + (size_t)N * 64); // 16384
  unsigned short*     Wp2     = Wp1 + 16384;                           // 16384
  int*                csr     = (int*)(Wp2 + 16384);                   // E
  float*              dis     = (float*)(csr + E);                     // N
  float*              h3p     = dis + N;                               // N
  int*                deg     = (int*)(h3p + N);                       // N   } zeroed
  unsigned long long* status  = (unsigned long long*)(deg + N);        // nb  } zeroed
  int*                dyn_ctr = (int*)(status + nb);                   // 2   } zeroed
  int*                row_ptr = dyn_ctr + 2;                           // N+1

  const size_t zero_bytes = (size_t)N * 4 + (size_t)nb * 8 + 8;

  const int cb = (E / 4 + 255) / 256;       // 586 count/fill blocks
  const int agg_blocks = (N + 15) / 16;     // 3125
  const int out_blocks = (N + 31) / 32;     // 1563
  const int nTiles = (N + 31) / 32;         // 1563
  const int gemm_blocks = (nTiles + 3) / 4; // 391

  hipMemsetAsync(deg, 0, zero_bytes, stream);
  k_count_pack<<<cb + 16, 256, 0, stream>>>(dst, deg, E, cb, W1, Wp1, W2, Wp2);
  k_scan<<<nb, 256, 0, stream>>>(deg, row_ptr, dis, status, dyn_ctr, N);
  k_fill_gemm1<<<cb + gemm_blocks, 256, 0, stream>>>(src, dst, row_ptr, csr, E, cb,
                                                     x, (const __bf16*)Wp1, dis,
                                                     (unsigned short*)Hb, nTiles, N);
  k_agg_ln<0><<<agg_blocks, 256, 0, stream>>>(Hb, row_ptr, csr, dis, b1, gamma, beta,
                                              nullptr, nullptr, Bbuf, N);
  k_gemm2<<<gemm_blocks, 256, 0, stream>>>(Bbuf, (const __bf16*)Wp2, dis,
                                           (unsigned short*)Hb, nTiles, N);
  k_agg_ln<1><<<agg_blocks, 256, 0, stream>>>(Hb, row_ptr, csr, dis, b2, gamma, beta,
                                              W3, h3p, Bbuf, N);
  k_out<<<out_blocks, 256, 0, stream>>>(h3p, row_ptr, csr, dis, b3, out, N);
}

// Round 8
// 216.731 us; speedup vs baseline: 16.3456x; 1.1025x over previous
//
#include <hip/hip_runtime.h>

#define F 128

typedef __attribute__((ext_vector_type(8))) __bf16 bf16x8;
typedef __attribute__((ext_vector_type(4))) float f32x4;

__device__ __forceinline__ float bflo(unsigned u) { return __uint_as_float(u << 16); }
__device__ __forceinline__ float bfhi(unsigned u) { return __uint_as_float(u & 0xffff0000u); }
__device__ __forceinline__ unsigned short bfbits(float f) {
  __bf16 h = (__bf16)f;
  union { __bf16 b; unsigned short s; } v; v.b = h; return v.s;
}
__device__ __forceinline__ unsigned packbf(float a, float b) {
  return (unsigned)bfbits(a) | ((unsigned)bfbits(b) << 16);
}

// ========== K_A: histogram (capturing slots)  ∪  W1 pack  ∪  W2 pack ==========
__device__ __forceinline__ void pack_body(const float* __restrict__ W,
                                          unsigned short* __restrict__ Wp, int idx) {
  int l = idx & 63, ct = idx >> 6, t = ct & 3, c = ct >> 2;
  int q = l >> 4, m = l & 15;
  #pragma unroll
  for (int j = 0; j < 8; ++j)
    Wp[idx * 8 + j] = bfbits(W[(t * 32 + q * 8 + j) * F + c * 16 + m]);
}

__global__ __launch_bounds__(256) void k_count_pack(const int* __restrict__ dst,
                                                    int* __restrict__ deg,
                                                    int* __restrict__ slot, int E, int cb,
                                                    const float* __restrict__ W1,
                                                    unsigned short* __restrict__ Wp1,
                                                    const float* __restrict__ W2,
                                                    unsigned short* __restrict__ Wp2) {
  int b = blockIdx.x;
  if (b < cb) {
    int base = (b * 256 + threadIdx.x) * 4;
    if (base + 3 < E) {
      int4 d = *(const int4*)(dst + base);
      int s0 = atomicAdd(&deg[d.x], 1);
      int s1 = atomicAdd(&deg[d.y], 1);
      int s2 = atomicAdd(&deg[d.z], 1);
      int s3 = atomicAdd(&deg[d.w], 1);
      *(int4*)(slot + base) = make_int4(s0, s1, s2, s3);
    } else {
      for (int k = base; k < E; ++k) slot[k] = atomicAdd(&deg[dst[k]], 1);
    }
  } else if (b < cb + 8) {
    pack_body(W1, Wp1, (b - cb) * 256 + threadIdx.x);
  } else {
    pack_body(W2, Wp2, (b - cb - 8) * 256 + threadIdx.x);
  }
}

// ========== single-kernel decoupled-lookback scan (+ dis = rsqrt(deg+1)) ==========
__global__ __launch_bounds__(256) void k_scan(const int* __restrict__ deg,
                                              int* __restrict__ row_ptr,
                                              float* __restrict__ dis,
                                              unsigned long long* __restrict__ status,
                                              int* __restrict__ dyn_ctr, int N) {
  __shared__ int s_bid;
  if (threadIdx.x == 0) s_bid = atomicAdd(dyn_ctr, 1);
  __syncthreads();
  const int bid = s_bid;
  int i = bid * 256 + threadIdx.x;
  int lane = threadIdx.x & 63, wid = threadIdx.x >> 6;
  int d = (i < N) ? deg[i] : 0;
  if (i < N) dis[i] = rsqrtf((float)d + 1.0f);
  int v = d;
  #pragma unroll
  for (int o = 1; o < 64; o <<= 1) {
    int t = __shfl_up(v, o);
    if (lane >= o) v += t;
  }
  __shared__ int wsum[4];
  __shared__ int s_excl;
  if (lane == 63) wsum[wid] = v;
  __syncthreads();
  if (threadIdx.x == 0) {
    int run = 0;
    #pragma unroll
    for (int w = 0; w < 4; ++w) { run += wsum[w]; wsum[w] = run; }
    int total = run;
    unsigned long long st = ((unsigned long long)(bid == 0 ? 2 : 1) << 32) |
                            (unsigned long long)(unsigned)total;
    atomicExch(&status[bid], st);
    int excl = 0;
    if (bid > 0) {
      int j = bid - 1;
      while (true) {
        unsigned long long s = atomicAdd(&status[j], 0ULL);
        unsigned flag = (unsigned)(s >> 32);
        if (flag == 0) { __builtin_amdgcn_s_sleep(1); continue; }
        excl += (int)(unsigned)s;
        if (flag == 2) break;
        --j;
      }
      atomicExch(&status[bid], (2ULL << 32) | (unsigned long long)(unsigned)(excl + total));
    }
    s_excl = excl;
  }
  __syncthreads();
  int excl = s_excl;
  if (wid > 0) v += wsum[wid - 1];
  if (i < N) row_ptr[i + 1] = excl + v;
  if (i == 0) row_ptr[0] = 0;
}

// ========== K_B: layer-1 GEMM  ∪  atomic-free CSR fill ==========
template<int F32A>
__device__ __forceinline__ bf16x8 load_frag(const void* A, int row, int off) {
  if (F32A) {
    const float* a = (const float*)A + (size_t)row * F + off;
    float4 u = *(const float4*)a, v = *(const float4*)(a + 4);
    bf16x8 r;
    r[0] = (__bf16)u.x; r[1] = (__bf16)u.y; r[2] = (__bf16)u.z; r[3] = (__bf16)u.w;
    r[4] = (__bf16)v.x; r[5] = (__bf16)v.y; r[6] = (__bf16)v.z; r[7] = (__bf16)v.w;
    return r;
  } else {
    return *(const bf16x8*)((const __bf16*)A + (size_t)row * F + off);
  }
}

// GEMM body: H'[row] = bf16( (A[row]@W) * dis[row] )  — dis folded into rows
template<int F32A>
__device__ __forceinline__ void gemm_body(const void* __restrict__ A,
                                          const __bf16* __restrict__ Wp,
                                          const float* __restrict__ dis,
                                          unsigned short* __restrict__ H,
                                          int gid, int tid, int N) {
  int lane = tid & 63, m = lane & 15, q = lane >> 4;
  const int row0 = gid * 32;
  const bool has2 = (row0 + 16) < N;
  f32x4 acc[2][8];
  #pragma unroll
  for (int h = 0; h < 2; ++h)
    #pragma unroll
    for (int c = 0; c < 8; ++c) acc[h][c] = (f32x4){0.f, 0.f, 0.f, 0.f};

  const int r0 = row0 + m, r1 = row0 + 16 + m;
  #pragma unroll 1
  for (int t = 0; t < 4; ++t) {
    bf16x8 a0 = load_frag<F32A>(A, r0, q * 8 + t * 32);
    bf16x8 a1 = has2 ? load_frag<F32A>(A, r1, q * 8 + t * 32) : a0;
    #pragma unroll
    for (int c = 0; c < 8; ++c) {
      bf16x8 w = *(const bf16x8*)(Wp + ((size_t)(c * 4 + t) * 64 + lane) * 8);
      acc[0][c] = __builtin_amdgcn_mfma_f32_16x16x32_bf16(a0, w, acc[0][c], 0, 0, 0);
      acc[1][c] = __builtin_amdgcn_mfma_f32_16x16x32_bf16(a1, w, acc[1][c], 0, 0, 0);
    }
  }
  float dr0[4], dr1[4];
  #pragma unroll
  for (int r = 0; r < 4; ++r) {
    dr0[r] = dis[row0 + q * 4 + r];
    dr1[r] = has2 ? dis[row0 + 16 + q * 4 + r] : 1.f;
  }
  #pragma unroll
  for (int c = 0; c < 8; ++c)
    #pragma unroll
    for (int r = 0; r < 4; ++r)
      H[(size_t)(row0 + q * 4 + r) * F + c * 16 + m] = bfbits(acc[0][c][r] * dr0[r]);
  if (has2) {
    #pragma unroll
    for (int c = 0; c < 8; ++c)
      #pragma unroll
      for (int r = 0; r < 4; ++r)
        H[(size_t)(row0 + 16 + q * 4 + r) * F + c * 16 + m] = bfbits(acc[1][c][r] * dr1[r]);
  }
}

__global__ __launch_bounds__(256) void k_gemm1_fill(const int* __restrict__ src,
                                                    const int* __restrict__ dst,
                                                    const int* __restrict__ slot,
                                                    const int* __restrict__ rp,
                                                    int* __restrict__ csr_src, int E, int gb,
                                                    const float* __restrict__ x,
                                                    const __bf16* __restrict__ Wp1,
                                                    const float* __restrict__ dis,
                                                    unsigned short* __restrict__ H,
                                                    int nTiles, int N) {
  int b = blockIdx.x;
  if (b < gb) {
    int gid = b * 4 + (threadIdx.x >> 6);
    if (gid < nTiles) gemm_body<1>(x, Wp1, dis, H, gid, threadIdx.x, N);
  } else {
    int base = ((b - gb) * 256 + threadIdx.x) * 4;
    if (base + 3 < E) {
      int4 s = *(const int4*)(src + base);
      int4 d = *(const int4*)(dst + base);
      int4 sl = *(const int4*)(slot + base);
      csr_src[rp[d.x] + sl.x] = s.x;
      csr_src[rp[d.y] + sl.y] = s.y;
      csr_src[rp[d.z] + sl.z] = s.z;
      csr_src[rp[d.w] + sl.w] = s.w;
    } else {
      for (int k = base; k < E; ++k) csr_src[rp[dst[k]] + slot[k]] = src[k];
    }
  }
}

__global__ __launch_bounds__(256) void k_gemm2(const void* __restrict__ A,
                                               const __bf16* __restrict__ Wp,
                                               const float* __restrict__ dis,
                                               unsigned short* __restrict__ H,
                                               int nTiles, int N) {
  int gid = blockIdx.x * 4 + (threadIdx.x >> 6);
  if (gid < nTiles) gemm_body<0>(A, Wp, dis, H, gid, threadIdx.x, N);
}

// ===== gather-agg (pure row sum, 4-deep chains) + bias + LN + ReLU (+ W3 dot) =====
// 16-lane group per node; lane covers 8 features via one uint4 gather per edge.
template<int FUSE3>
__global__ __launch_bounds__(256) void k_agg_ln(const unsigned* __restrict__ Hb,
                                                const int* __restrict__ rp,
                                                const int* __restrict__ csr,
                                                const float* __restrict__ dis,
                                                const float* __restrict__ bias,
                                                const float* __restrict__ gamma,
                                                const float* __restrict__ beta,
                                                const float* __restrict__ W3,
                                                float* __restrict__ h3p,
                                                unsigned* __restrict__ Bb, int N) {
  int tid = threadIdx.x;
  int l = tid & 15;
  int n = blockIdx.x * 16 + (tid >> 4);
  if (n >= N) return;
  float dn = dis[n];
  int e = rp[n], end = rp[n + 1];

  float a[8] = {}, b[8] = {}, c[8] = {}, d[8] = {};
  for (; e + 4 <= end; e += 4) {
    int s0 = csr[e], s1 = csr[e + 1], s2 = csr[e + 2], s3 = csr[e + 3];
    uint4 r0 = *(const uint4*)(Hb + (size_t)s0 * 64 + l * 4);
    uint4 r1 = *(const uint4*)(Hb + (size_t)s1 * 64 + l * 4);
    uint4 r2 = *(const uint4*)(Hb + (size_t)s2 * 64 + l * 4);
    uint4 r3 = *(const uint4*)(Hb + (size_t)s3 * 64 + l * 4);
    a[0] += bflo(r0.x); a[1] += bfhi(r0.x); a[2] += bflo(r0.y); a[3] += bfhi(r0.y);
    a[4] += bflo(r0.z); a[5] += bfhi(r0.z); a[6] += bflo(r0.w); a[7] += bfhi(r0.w);
    b[0] += bflo(r1.x); b[1] += bfhi(r1.x); b[2] += bflo(r1.y); b[3] += bfhi(r1.y);
    b[4] += bflo(r1.z); b[5] += bfhi(r1.z); b[6] += bflo(r1.w); b[7] += bfhi(r1.w);
    c[0] += bflo(r2.x); c[1] += bfhi(r2.x); c[2] += bflo(r2.y); c[3] += bfhi(r2.y);
    c[4] += bflo(r2.z); c[5] += bfhi(r2.z); c[6] += bflo(r2.w); c[7] += bfhi(r2.w);
    d[0] += bflo(r3.x); d[1] += bfhi(r3.x); d[2] += bflo(r3.y); d[3] += bfhi(r3.y);
    d[4] += bflo(r3.z); d[5] += bfhi(r3.z); d[6] += bflo(r3.w); d[7] += bfhi(r3.w);
  }
  for (; e < end; ++e) {
    int s0 = csr[e];
    uint4 r0 = *(const uint4*)(Hb + (size_t)s0 * 64 + l * 4);
    a[0] += bflo(r0.x); a[1] += bfhi(r0.x); a[2] += bflo(r0.y); a[3] += bfhi(r0.y);
    a[4] += bflo(r0.z); a[5] += bfhi(r0.z); a[6] += bflo(r0.w); a[7] += bfhi(r0.w);
  }

  uint4 su = *(const uint4*)(Hb + (size_t)n * 64 + l * 4);
  float self[8] = { bflo(su.x), bfhi(su.x), bflo(su.y), bfhi(su.y),
                    bflo(su.z), bfhi(su.z), bflo(su.w), bfhi(su.w) };
  float4 bi0 = ((const float4*)bias)[l * 2], bi1 = ((const float4*)bias)[l * 2 + 1];
  float bi[8] = { bi0.x, bi0.y, bi0.z, bi0.w, bi1.x, bi1.y, bi1.z, bi1.w };
  float v[8];
  float s = 0.f;
  #pragma unroll
  for (int k = 0; k < 8; ++k) {
    v[k] = ((a[k] + b[k]) + (c[k] + d[k]) + self[k]) * dn + bi[k];
    s += v[k];
  }
  #pragma unroll
  for (int o = 1; o < 16; o <<= 1) s += __shfl_xor(s, o);
  float mu = s * (1.0f / F);
  float sq = 0.f;
  #pragma unroll
  for (int k = 0; k < 8; ++k) { v[k] -= mu; sq += v[k] * v[k]; }
  #pragma unroll
  for (int o = 1; o < 16; o <<= 1) sq += __shfl_xor(sq, o);
  float inv = rsqrtf(sq * (1.0f / F) + 1e-5f);

  float4 ga0 = ((const float4*)gamma)[l * 2], ga1 = ((const float4*)gamma)[l * 2 + 1];
  float4 be0 = ((const float4*)beta)[l * 2],  be1 = ((const float4*)beta)[l * 2 + 1];
  float ga[8] = { ga0.x, ga0.y, ga0.z, ga0.w, ga1.x, ga1.y, ga1.z, ga1.w };
  float be[8] = { be0.x, be0.y, be0.z, be0.w, be1.x, be1.y, be1.z, be1.w };
  float o8[8];
  #pragma unroll
  for (int k = 0; k < 8; ++k) o8[k] = fmaxf(v[k] * inv * ga[k] + be[k], 0.f);

  uint4 outv;
  outv.x = packbf(o8[0], o8[1]); outv.y = packbf(o8[2], o8[3]);
  outv.z = packbf(o8[4], o8[5]); outv.w = packbf(o8[6], o8[7]);
  *(uint4*)(Bb + (size_t)n * 64 + l * 4) = outv;

  if (FUSE3) {
    float4 w30 = ((const float4*)W3)[l * 2], w31 = ((const float4*)W3)[l * 2 + 1];
    float w3[8] = { w30.x, w30.y, w30.z, w30.w, w31.x, w31.y, w31.z, w31.w };
    float s3 = 0.f;
    #pragma unroll
    for (int k = 0; k < 8; ++k) {
      float q = (k & 1) ? bfhi(((unsigned*)&outv)[k >> 1]) : bflo(((unsigned*)&outv)[k >> 1]);
      s3 += q * w3[k];
    }
    #pragma unroll
    for (int o = 1; o < 16; o <<= 1) s3 += __shfl_xor(s3, o);
    if (l == 0) h3p[n] = s3 * dn;
  }
}

// ========== output gather: out[n] = dn*(sum h3'[src] + h3'[n]) + b3 ==========
__global__ __launch_bounds__(256) void k_out(const float* __restrict__ h3p,
                                             const int* __restrict__ rp,
                                             const int* __restrict__ csr,
                                             const float* __restrict__ dis,
                                             const float* __restrict__ b3,
                                             float* __restrict__ out, int N) {
  int tid = threadIdx.x;
  int l = tid & 7;
  int n = blockIdx.x * 32 + (tid >> 3);
  if (n >= N) return;
  float dn = dis[n];
  int beg = rp[n], end = rp[n + 1];
  float s = 0.0f;
  for (int e = beg + l; e < end; e += 8) s += h3p[csr[e]];
  #pragma unroll
  for (int o = 1; o < 8; o <<= 1) s += __shfl_xor(s, o);
  if (l == 0) out[n] = (s + h3p[n]) * dn + b3[0];
}

// ================= launch =================
extern "C" void kernel_launch(void* const* d_in, const int* in_sizes, int n_in,
                              void* d_out, int out_size, void* d_ws, size_t ws_size,
                              hipStream_t stream) {
  const float* x     = (const float*)d_in[0];
  const int*   ei    = (const int*)d_in[1];
  const float* W1    = (const float*)d_in[2];
  const float* b1    = (const float*)d_in[3];
  const float* W2    = (const float*)d_in[4];
  const float* b2    = (const float*)d_in[5];
  const float* W3    = (const float*)d_in[6];
  const float* b3    = (const float*)d_in[7];
  const float* gamma = (const float*)d_in[8];
  const float* beta  = (const float*)d_in[9];
  float* out = (float*)d_out;

  const int N = in_sizes[0] / F;   // 50000
  const int E = in_sizes[1] / 2;   // 600000
  const int* src = ei;
  const int* dst = ei + E;

  const int nb = (N + 255) / 256;           // 196 scan blocks

  unsigned*           Hb      = (unsigned*)d_ws;                       // N*64
  unsigned*           Bbuf    = Hb + (size_t)N * 64;                   // N*64
  unsigned short*     Wp1     = (unsigned short*)(Bbuf + (size_t)N * 64); // 16384
  unsigned short*     Wp2     = Wp1 + 16384;                           // 16384
  int*                csr     = (int*)(Wp2 + 16384);                   // E
  int*                slot    = csr + E;                               // E
  float*              dis     = (float*)(slot + E);                    // N
  float*              h3p     = dis + N;                               // N
  int*                deg     = (int*)(h3p + N);                       // N   } zeroed
  unsigned long long* status  = (unsigned long long*)(deg + N);        // nb  } zeroed
  int*                dyn_ctr = (int*)(status + nb);                   // 2   } zeroed
  int*                row_ptr = dyn_ctr + 2;                           // N+1

  const size_t zero_bytes = (size_t)N * 4 + (size_t)nb * 8 + 8;

  const int cb = (E / 4 + 255) / 256;       // 586 count/fill blocks
  const int agg_blocks = (N + 15) / 16;     // 3125
  const int out_blocks = (N + 31) / 32;     // 1563
  const int nTiles = (N + 31) / 32;         // 1563
  const int gemm_blocks = (nTiles + 3) / 4; // 391

  hipMemsetAsync(deg, 0, zero_bytes, stream);
  k_count_pack<<<cb + 16, 256, 0, stream>>>(dst, deg, slot, E, cb, W1, Wp1, W2, Wp2);
  k_scan<<<nb, 256, 0, stream>>>(deg, row_ptr, dis, status, dyn_ctr, N);
  k_gemm1_fill<<<gemm_blocks + cb, 256, 0, stream>>>(src, dst, slot, row_ptr, csr, E,
                                                     gemm_blocks, x, (const __bf16*)Wp1,
                                                     dis, (unsigned short*)Hb, nTiles, N);
  k_agg_ln<0><<<agg_blocks, 256, 0, stream>>>(Hb, row_ptr, csr, dis, b1, gamma, beta,
                                              nullptr, nullptr, Bbuf, N);
  k_gemm2<<<gemm_blocks, 256, 0, stream>>>(Bbuf, (const __bf16*)Wp2, dis,
                                           (unsigned short*)Hb, nTiles, N);
  k_agg_ln<1><<<agg_blocks, 256, 0, stream>>>(Hb, row_ptr, csr, dis, b2, gamma, beta,
                                              W3, h3p, Bbuf, N);
  k_out<<<out_blocks, 256, 0, stream>>>(h3p, row_ptr, csr, dis, b3, out, N);
}

// Round 9
// 208.927 us; speedup vs baseline: 16.9561x; 1.0374x over previous
//
#include <hip/hip_runtime.h>

#define F 128

typedef __attribute__((ext_vector_type(8))) __bf16 bf16x8;
typedef __attribute__((ext_vector_type(4))) float f32x4;

__device__ __forceinline__ float bflo(unsigned u) { return __uint_as_float(u << 16); }
__device__ __forceinline__ float bfhi(unsigned u) { return __uint_as_float(u & 0xffff0000u); }
__device__ __forceinline__ unsigned short bfbits(float f) {
  __bf16 h = (__bf16)f;
  union { __bf16 b; unsigned short s; } v; v.b = h; return v.s;
}
__device__ __forceinline__ unsigned packbf(float a, float b) {
  return (unsigned)bfbits(a) | ((unsigned)bfbits(b) << 16);
}

// ========== K_A: histogram (capturing slots)  ∪  W1 pack  ∪  W2 pack ==========
__device__ __forceinline__ void pack_body(const float* __restrict__ W,
                                          unsigned short* __restrict__ Wp, int idx) {
  int l = idx & 63, ct = idx >> 6, t = ct & 3, c = ct >> 2;
  int q = l >> 4, m = l & 15;
  #pragma unroll
  for (int j = 0; j < 8; ++j)
    Wp[idx * 8 + j] = bfbits(W[(t * 32 + q * 8 + j) * F + c * 16 + m]);
}

__global__ __launch_bounds__(256) void k_count_pack(const int* __restrict__ dst,
                                                    int* __restrict__ deg,
                                                    int* __restrict__ slot, int E, int cb,
                                                    const float* __restrict__ W1,
                                                    unsigned short* __restrict__ Wp1,
                                                    const float* __restrict__ W2,
                                                    unsigned short* __restrict__ Wp2) {
  int b = blockIdx.x;
  if (b < cb) {
    int base = (b * 256 + threadIdx.x) * 4;
    if (base + 3 < E) {
      int4 d = *(const int4*)(dst + base);
      int s0 = atomicAdd(&deg[d.x], 1);
      int s1 = atomicAdd(&deg[d.y], 1);
      int s2 = atomicAdd(&deg[d.z], 1);
      int s3 = atomicAdd(&deg[d.w], 1);
      *(int4*)(slot + base) = make_int4(s0, s1, s2, s3);
    } else {
      for (int k = base; k < E; ++k) slot[k] = atomicAdd(&deg[dst[k]], 1);
    }
  } else if (b < cb + 8) {
    pack_body(W1, Wp1, (b - cb) * 256 + threadIdx.x);
  } else {
    pack_body(W2, Wp2, (b - cb - 8) * 256 + threadIdx.x);
  }
}

// ========== single-kernel decoupled-lookback scan (+ dis = rsqrt(deg+1)) ==========
__global__ __launch_bounds__(256) void k_scan(const int* __restrict__ deg,
                                              int* __restrict__ row_ptr,
                                              float* __restrict__ dis,
                                              unsigned long long* __restrict__ status,
                                              int* __restrict__ dyn_ctr, int N) {
  __shared__ int s_bid;
  if (threadIdx.x == 0) s_bid = atomicAdd(dyn_ctr, 1);
  __syncthreads();
  const int bid = s_bid;
  int i = bid * 256 + threadIdx.x;
  int lane = threadIdx.x & 63, wid = threadIdx.x >> 6;
  int d = (i < N) ? deg[i] : 0;
  if (i < N) dis[i] = rsqrtf((float)d + 1.0f);
  int v = d;
  #pragma unroll
  for (int o = 1; o < 64; o <<= 1) {
    int t = __shfl_up(v, o);
    if (lane >= o) v += t;
  }
  __shared__ int wsum[4];
  __shared__ int s_excl;
  if (lane == 63) wsum[wid] = v;
  __syncthreads();
  if (threadIdx.x == 0) {
    int run = 0;
    #pragma unroll
    for (int w = 0; w < 4; ++w) { run += wsum[w]; wsum[w] = run; }
    int total = run;
    unsigned long long st = ((unsigned long long)(bid == 0 ? 2 : 1) << 32) |
                            (unsigned long long)(unsigned)total;
    atomicExch(&status[bid], st);
    int excl = 0;
    if (bid > 0) {
      int j = bid - 1;
      while (true) {
        unsigned long long s = atomicAdd(&status[j], 0ULL);
        unsigned flag = (unsigned)(s >> 32);
        if (flag == 0) { __builtin_amdgcn_s_sleep(1); continue; }
        excl += (int)(unsigned)s;
        if (flag == 2) break;
        --j;
      }
      atomicExch(&status[bid], (2ULL << 32) | (unsigned long long)(unsigned)(excl + total));
    }
    s_excl = excl;
  }
  __syncthreads();
  int excl = s_excl;
  if (wid > 0) v += wsum[wid - 1];
  if (i < N) row_ptr[i + 1] = excl + v;
  if (i == 0) row_ptr[0] = 0;
}

// ========== K_B: layer-1 GEMM  ∪  atomic-free CSR fill ==========
template<int F32A>
__device__ __forceinline__ bf16x8 load_frag(const void* A, int row, int off) {
  if (F32A) {
    const float* a = (const float*)A + (size_t)row * F + off;
    float4 u = *(const float4*)a, v = *(const float4*)(a + 4);
    bf16x8 r;
    r[0] = (__bf16)u.x; r[1] = (__bf16)u.y; r[2] = (__bf16)u.z; r[3] = (__bf16)u.w;
    r[4] = (__bf16)v.x; r[5] = (__bf16)v.y; r[6] = (__bf16)v.z; r[7] = (__bf16)v.w;
    return r;
  } else {
    return *(const bf16x8*)((const __bf16*)A + (size_t)row * F + off);
  }
}

// GEMM body (32 rows/wave): H'[row] = bf16( (A[row]@W) * dis[row] )
template<int F32A>
__device__ __forceinline__ void gemm_body(const void* __restrict__ A,
                                          const __bf16* __restrict__ Wp,
                                          const float* __restrict__ dis,
                                          unsigned short* __restrict__ H,
                                          int gid, int tid, int N) {
  int lane = tid & 63, m = lane & 15, q = lane >> 4;
  const int row0 = gid * 32;
  const bool has2 = (row0 + 16) < N;
  f32x4 acc[2][8];
  #pragma unroll
  for (int h = 0; h < 2; ++h)
    #pragma unroll
    for (int c = 0; c < 8; ++c) acc[h][c] = (f32x4){0.f, 0.f, 0.f, 0.f};

  const int r0 = row0 + m, r1 = row0 + 16 + m;
  #pragma unroll 1
  for (int t = 0; t < 4; ++t) {
    bf16x8 a0 = load_frag<F32A>(A, r0, q * 8 + t * 32);
    bf16x8 a1 = has2 ? load_frag<F32A>(A, r1, q * 8 + t * 32) : a0;
    #pragma unroll
    for (int c = 0; c < 8; ++c) {
      bf16x8 w = *(const bf16x8*)(Wp + ((size_t)(c * 4 + t) * 64 + lane) * 8);
      acc[0][c] = __builtin_amdgcn_mfma_f32_16x16x32_bf16(a0, w, acc[0][c], 0, 0, 0);
      acc[1][c] = __builtin_amdgcn_mfma_f32_16x16x32_bf16(a1, w, acc[1][c], 0, 0, 0);
    }
  }
  float dr0[4], dr1[4];
  #pragma unroll
  for (int r = 0; r < 4; ++r) {
    dr0[r] = dis[row0 + q * 4 + r];
    dr1[r] = has2 ? dis[row0 + 16 + q * 4 + r] : 1.f;
  }
  #pragma unroll
  for (int c = 0; c < 8; ++c)
    #pragma unroll
    for (int r = 0; r < 4; ++r)
      H[(size_t)(row0 + q * 4 + r) * F + c * 16 + m] = bfbits(acc[0][c][r] * dr0[r]);
  if (has2) {
    #pragma unroll
    for (int c = 0; c < 8; ++c)
      #pragma unroll
      for (int r = 0; r < 4; ++r)
        H[(size_t)(row0 + 16 + q * 4 + r) * F + c * 16 + m] = bfbits(acc[1][c][r] * dr1[r]);
  }
}

__global__ __launch_bounds__(256) void k_gemm1_fill(const int* __restrict__ src,
                                                    const int* __restrict__ dst,
                                                    const int* __restrict__ slot,
                                                    const int* __restrict__ rp,
                                                    int* __restrict__ csr_src, int E, int gb,
                                                    const float* __restrict__ x,
                                                    const __bf16* __restrict__ Wp1,
                                                    const float* __restrict__ dis,
                                                    unsigned short* __restrict__ H,
                                                    int nTiles, int N) {
  int b = blockIdx.x;
  if (b < gb) {
    int gid = b * 4 + (threadIdx.x >> 6);
    if (gid < nTiles) gemm_body<1>(x, Wp1, dis, H, gid, threadIdx.x, N);
  } else {
    int base = ((b - gb) * 256 + threadIdx.x) * 4;
    if (base + 3 < E) {
      int4 s = *(const int4*)(src + base);
      int4 d = *(const int4*)(dst + base);
      int4 sl = *(const int4*)(slot + base);
      csr_src[rp[d.x] + sl.x] = s.x;
      csr_src[rp[d.y] + sl.y] = s.y;
      csr_src[rp[d.z] + sl.z] = s.z;
      csr_src[rp[d.w] + sl.w] = s.w;
    } else {
      for (int k = base; k < E; ++k) csr_src[rp[dst[k]] + slot[k]] = src[k];
    }
  }
}

// ===== shared agg helper: gather row-sum (4-deep) + bias + LN + ReLU =====
// Returns packed bf16 pair x4 for this lane (features 8l..8l+7).
__device__ __forceinline__ uint4 agg_ln_row(const unsigned* __restrict__ Hb,
                                            const int* __restrict__ csr,
                                            int e, int end, int n, float dn, int l,
                                            const float* __restrict__ bias,
                                            const float* __restrict__ gamma,
                                            const float* __restrict__ beta) {
  float a[8] = {}, b[8] = {}, c[8] = {}, d[8] = {};
  for (; e + 4 <= end; e += 4) {
    int s0 = csr[e], s1 = csr[e + 1], s2 = csr[e + 2], s3 = csr[e + 3];
    uint4 r0 = *(const uint4*)(Hb + (size_t)s0 * 64 + l * 4);
    uint4 r1 = *(const uint4*)(Hb + (size_t)s1 * 64 + l * 4);
    uint4 r2 = *(const uint4*)(Hb + (size_t)s2 * 64 + l * 4);
    uint4 r3 = *(const uint4*)(Hb + (size_t)s3 * 64 + l * 4);
    a[0] += bflo(r0.x); a[1] += bfhi(r0.x); a[2] += bflo(r0.y); a[3] += bfhi(r0.y);
    a[4] += bflo(r0.z); a[5] += bfhi(r0.z); a[6] += bflo(r0.w); a[7] += bfhi(r0.w);
    b[0] += bflo(r1.x); b[1] += bfhi(r1.x); b[2] += bflo(r1.y); b[3] += bfhi(r1.y);
    b[4] += bflo(r1.z); b[5] += bfhi(r1.z); b[6] += bflo(r1.w); b[7] += bfhi(r1.w);
    c[0] += bflo(r2.x); c[1] += bfhi(r2.x); c[2] += bflo(r2.y); c[3] += bfhi(r2.y);
    c[4] += bflo(r2.z); c[5] += bfhi(r2.z); c[6] += bflo(r2.w); c[7] += bfhi(r2.w);
    d[0] += bflo(r3.x); d[1] += bfhi(r3.x); d[2] += bflo(r3.y); d[3] += bfhi(r3.y);
    d[4] += bflo(r3.z); d[5] += bfhi(r3.z); d[6] += bflo(r3.w); d[7] += bfhi(r3.w);
  }
  for (; e < end; ++e) {
    int s0 = csr[e];
    uint4 r0 = *(const uint4*)(Hb + (size_t)s0 * 64 + l * 4);
    a[0] += bflo(r0.x); a[1] += bfhi(r0.x); a[2] += bflo(r0.y); a[3] += bfhi(r0.y);
    a[4] += bflo(r0.z); a[5] += bfhi(r0.z); a[6] += bflo(r0.w); a[7] += bfhi(r0.w);
  }
  uint4 su = *(const uint4*)(Hb + (size_t)n * 64 + l * 4);
  float self[8] = { bflo(su.x), bfhi(su.x), bflo(su.y), bfhi(su.y),
                    bflo(su.z), bfhi(su.z), bflo(su.w), bfhi(su.w) };
  float4 bi0 = ((const float4*)bias)[l * 2], bi1 = ((const float4*)bias)[l * 2 + 1];
  float bi[8] = { bi0.x, bi0.y, bi0.z, bi0.w, bi1.x, bi1.y, bi1.z, bi1.w };
  float v[8];
  float s = 0.f;
  #pragma unroll
  for (int k = 0; k < 8; ++k) {
    v[k] = ((a[k] + b[k]) + (c[k] + d[k]) + self[k]) * dn + bi[k];
    s += v[k];
  }
  #pragma unroll
  for (int o = 1; o < 16; o <<= 1) s += __shfl_xor(s, o);
  float mu = s * (1.0f / F);
  float sq = 0.f;
  #pragma unroll
  for (int k = 0; k < 8; ++k) { v[k] -= mu; sq += v[k] * v[k]; }
  #pragma unroll
  for (int o = 1; o < 16; o <<= 1) sq += __shfl_xor(sq, o);
  float inv = rsqrtf(sq * (1.0f / F) + 1e-5f);
  float4 ga0 = ((const float4*)gamma)[l * 2], ga1 = ((const float4*)gamma)[l * 2 + 1];
  float4 be0 = ((const float4*)beta)[l * 2],  be1 = ((const float4*)beta)[l * 2 + 1];
  float ga[8] = { ga0.x, ga0.y, ga0.z, ga0.w, ga1.x, ga1.y, ga1.z, ga1.w };
  float be[8] = { be0.x, be0.y, be0.z, be0.w, be1.x, be1.y, be1.z, be1.w };
  float o8[8];
  #pragma unroll
  for (int k = 0; k < 8; ++k) o8[k] = fmaxf(v[k] * inv * ga[k] + be[k], 0.f);
  uint4 outv;
  outv.x = packbf(o8[0], o8[1]); outv.y = packbf(o8[2], o8[3]);
  outv.z = packbf(o8[4], o8[5]); outv.w = packbf(o8[6], o8[7]);
  return outv;
}

// ========== FUSED: agg+LN+ReLU (layer 1) -> LDS -> layer-2 GEMM ==========
// Block = 64 nodes. Agg: 4 passes x 16 groups of 16 lanes; LN rows -> LDS
// (row stride 272 B = 17x16: rows map 2-per-bank => conflict-free per m136).
// GEMM: 4 waves x 16-row MFMA tiles, A-frags via ds_read_b128.
// Writes H2' (dis-folded) to a DIFFERENT buffer than Hb (slower blocks still
// gather from Hb).
#define LROW 272
__global__ __launch_bounds__(256) void k_agg_gemm2(const unsigned* __restrict__ Hb,
                                                   const int* __restrict__ rp,
                                                   const int* __restrict__ csr,
                                                   const float* __restrict__ dis,
                                                   const float* __restrict__ bias,
                                                   const float* __restrict__ gamma,
                                                   const float* __restrict__ beta,
                                                   const __bf16* __restrict__ Wp2,
                                                   unsigned short* __restrict__ Hout,
                                                   int N) {
  __shared__ __align__(16) unsigned char lds[64 * LROW];
  const int tid = threadIdx.x;
  const int l = tid & 15, g = tid >> 4;
  const int node0 = blockIdx.x * 64;

  #pragma unroll 1
  for (int p = 0; p < 4; ++p) {
    int r = p * 16 + g;
    int n = node0 + r;
    if (n < N) {
      uint4 outv = agg_ln_row(Hb, csr, rp[n], rp[n + 1], n, dis[n], l, bias, gamma, beta);
      *(uint4*)(lds + r * LROW + l * 16) = outv;
    }
  }
  __syncthreads();

  const int lane = tid & 63, wv = tid >> 6;
  const int m = lane & 15, q = lane >> 4;
  const int row0 = node0 + wv * 16;
  if (row0 >= N) return;                 // N%16==0 -> full tiles only
  f32x4 acc[8];
  #pragma unroll
  for (int c = 0; c < 8; ++c) acc[c] = (f32x4){0.f, 0.f, 0.f, 0.f};
  const unsigned char* arow = lds + (wv * 16 + m) * LROW + q * 16;
  #pragma unroll 1
  for (int t = 0; t < 4; ++t) {
    bf16x8 a0 = *(const bf16x8*)(arow + t * 64);
    #pragma unroll
    for (int c = 0; c < 8; ++c) {
      bf16x8 w = *(const bf16x8*)(Wp2 + ((size_t)(c * 4 + t) * 64 + lane) * 8);
      acc[c] = __builtin_amdgcn_mfma_f32_16x16x32_bf16(a0, w, acc[c], 0, 0, 0);
    }
  }
  float dr[4];
  #pragma unroll
  for (int r = 0; r < 4; ++r) dr[r] = dis[row0 + q * 4 + r];
  #pragma unroll
  for (int c = 0; c < 8; ++c)
    #pragma unroll
    for (int r = 0; r < 4; ++r)
      Hout[(size_t)(row0 + q * 4 + r) * F + c * 16 + m] = bfbits(acc[c][r] * dr[r]);
}

// ===== layer-2 agg + LN + ReLU + fused W3 dot -> h3' (16-lane group/node) =====
__global__ __launch_bounds__(256) void k_agg_ln3(const unsigned* __restrict__ Hb,
                                                 const int* __restrict__ rp,
                                                 const int* __restrict__ csr,
                                                 const float* __restrict__ dis,
                                                 const float* __restrict__ bias,
                                                 const float* __restrict__ gamma,
                                                 const float* __restrict__ beta,
                                                 const float* __restrict__ W3,
                                                 float* __restrict__ h3p, int N) {
  int tid = threadIdx.x;
  int l = tid & 15;
  int n = blockIdx.x * 16 + (tid >> 4);
  if (n >= N) return;
  float dn = dis[n];
  uint4 outv = agg_ln_row(Hb, csr, rp[n], rp[n + 1], n, dn, l, bias, gamma, beta);
  float4 w30 = ((const float4*)W3)[l * 2], w31 = ((const float4*)W3)[l * 2 + 1];
  float w3[8] = { w30.x, w30.y, w30.z, w30.w, w31.x, w31.y, w31.z, w31.w };
  float s3 = bflo(outv.x) * w3[0] + bfhi(outv.x) * w3[1]
           + bflo(outv.y) * w3[2] + bfhi(outv.y) * w3[3]
           + bflo(outv.z) * w3[4] + bfhi(outv.z) * w3[5]
           + bflo(outv.w) * w3[6] + bfhi(outv.w) * w3[7];
  #pragma unroll
  for (int o = 1; o < 16; o <<= 1) s3 += __shfl_xor(s3, o);
  if (l == 0) h3p[n] = s3 * dn;
}

// ========== output gather: out[n] = dn*(sum h3'[src] + h3'[n]) + b3 ==========
__global__ __launch_bounds__(256) void k_out(const float* __restrict__ h3p,
                                             const int* __restrict__ rp,
                                             const int* __restrict__ csr,
                                             const float* __restrict__ dis,
                                             const float* __restrict__ b3,
                                             float* __restrict__ out, int N) {
  int tid = threadIdx.x;
  int l = tid & 7;
  int n = blockIdx.x * 32 + (tid >> 3);
  if (n >= N) return;
  float dn = dis[n];
  int beg = rp[n], end = rp[n + 1];
  float s = 0.0f;
  for (int e = beg + l; e < end; e += 8) s += h3p[csr[e]];
  #pragma unroll
  for (int o = 1; o < 8; o <<= 1) s += __shfl_xor(s, o);
  if (l == 0) out[n] = (s + h3p[n]) * dn + b3[0];
}

// ================= launch =================
extern "C" void kernel_launch(void* const* d_in, const int* in_sizes, int n_in,
                              void* d_out, int out_size, void* d_ws, size_t ws_size,
                              hipStream_t stream) {
  const float* x     = (const float*)d_in[0];
  const int*   ei    = (const int*)d_in[1];
  const float* W1    = (const float*)d_in[2];
  const float* b1    = (const float*)d_in[3];
  const float* W2    = (const float*)d_in[4];
  const float* b2    = (const float*)d_in[5];
  const float* W3    = (const float*)d_in[6];
  const float* b3    = (const float*)d_in[7];
  const float* gamma = (const float*)d_in[8];
  const float* beta  = (const float*)d_in[9];
  float* out = (float*)d_out;

  const int N = in_sizes[0] / F;   // 50000
  const int E = in_sizes[1] / 2;   // 600000
  const int* src = ei;
  const int* dst = ei + E;

  const int nb = (N + 255) / 256;           // 196 scan blocks

  unsigned*           Hb      = (unsigned*)d_ws;                       // N*64  (H1')
  unsigned*           Bbuf    = Hb + (size_t)N * 64;                   // N*64  (H2')
  unsigned short*     Wp1     = (unsigned short*)(Bbuf + (size_t)N * 64); // 16384
  unsigned short*     Wp2     = Wp1 + 16384;                           // 16384
  int*                csr     = (int*)(Wp2 + 16384);                   // E
  int*                slot    = csr + E;                               // E
  float*              dis     = (float*)(slot + E);                    // N
  float*              h3p     = dis + N;                               // N
  int*                deg     = (int*)(h3p + N);                       // N   } zeroed
  unsigned long long* status  = (unsigned long long*)(deg + N);        // nb  } zeroed
  int*                dyn_ctr = (int*)(status + nb);                   // 2   } zeroed
  int*                row_ptr = dyn_ctr + 2;                           // N+1

  const size_t zero_bytes = (size_t)N * 4 + (size_t)nb * 8 + 8;

  const int cb = (E / 4 + 255) / 256;       // 586 count/fill blocks
  const int fuse_blocks = (N + 63) / 64;    // 782
  const int agg_blocks = (N + 15) / 16;     // 3125
  const int out_blocks = (N + 31) / 32;     // 1563
  const int nTiles = (N + 31) / 32;         // 1563
  const int gemm_blocks = (nTiles + 3) / 4; // 391

  hipMemsetAsync(deg, 0, zero_bytes, stream);
  k_count_pack<<<cb + 16, 256, 0, stream>>>(dst, deg, slot, E, cb, W1, Wp1, W2, Wp2);
  k_scan<<<nb, 256, 0, stream>>>(deg, row_ptr, dis, status, dyn_ctr, N);
  k_gemm1_fill<<<gemm_blocks + cb, 256, 0, stream>>>(src, dst, slot, row_ptr, csr, E,
                                                     gemm_blocks, x, (const __bf16*)Wp1,
                                                     dis, (unsigned short*)Hb, nTiles, N);
  k_agg_gemm2<<<fuse_blocks, 256, 0, stream>>>(Hb, row_ptr, csr, dis, b1, gamma, beta,
                                               (const __bf16*)Wp2,
                                               (unsigned short*)Bbuf, N);
  k_agg_ln3<<<agg_blocks, 256, 0, stream>>>(Bbuf, row_ptr, csr, dis, b2, gamma, beta,
                                            W3, h3p, N);
  k_out<<<out_blocks, 256, 0, stream>>>(h3p, row_ptr, csr, dis, b3, out, N);
}